// Round 1
// 507.963 us; speedup vs baseline: 1.0183x; 1.0183x over previous
//
#include <hip/hip_runtime.h>
#include <hip/hip_bf16.h>

typedef __bf16 bf16_t;
typedef __bf16 bf16x8 __attribute__((ext_vector_type(8)));
typedef __bf16 bf16x4 __attribute__((ext_vector_type(4)));
typedef float f32x4 __attribute__((ext_vector_type(4)));

constexpr int kN = 512;       // nodes per sample
constexpr int kBZ = 32;       // batch
constexpr int kTC = 256;
constexpr int kE = 524288;
constexpr int kNTOT = 16384;  // kBZ*kN

// ---------------- front: weight convert + zero-init + lsr ----------------
// blocks [0,200): convert/zero. quads: c1w (32768), c2w (8192), counts zero (4096 int4),
//                 degsum zero (4096 float4), h1acc zero (2048 float4)
// blocks [200,4296): k_lsr body. P0=ls0+b0, P1=ls1+b1, Q0=lr0, Q1=lr1 per row (u = relu(t))
__global__ __launch_bounds__(256) void k_front(const float* __restrict__ c1w, const float* __restrict__ c2w,
                                               bf16_t* __restrict__ c1b, bf16_t* __restrict__ c2b,
                                               int* __restrict__ counts, float* __restrict__ degsum,
                                               float* __restrict__ h1acc,
                                               const float* __restrict__ tin, const float* __restrict__ fcw,
                                               const float* __restrict__ fcb, float4* __restrict__ lsr) {
    int b = blockIdx.x;
    if (b < 200) {
        int i = b * 256 + threadIdx.x;
        const int n0 = 32768, n1 = n0 + 8192, n2 = n1 + 4096, n3 = n2 + 4096, n4 = n3 + 2048;
        if (i < n0) {
            float4 v = ((const float4*)c1w)[i];
            bf16x4 o = {(bf16_t)v.x, (bf16_t)v.y, (bf16_t)v.z, (bf16_t)v.w};
            ((bf16x4*)c1b)[i] = o;
        } else if (i < n1) {
            int j = i - n0;
            float4 v = ((const float4*)c2w)[j];
            bf16x4 o = {(bf16_t)v.x, (bf16_t)v.y, (bf16_t)v.z, (bf16_t)v.w};
            ((bf16x4*)c2b)[j] = o;
        } else if (i < n2) {
            ((int4*)counts)[i - n1] = make_int4(0, 0, 0, 0);
        } else if (i < n3) {
            ((float4*)degsum)[i - n2] = make_float4(0.f, 0.f, 0.f, 0.f);
        } else if (i < n4) {
            ((float4*)h1acc)[i - n3] = make_float4(0.f, 0.f, 0.f, 0.f);
        }
    } else {
        int row = (b - 200) * 4 + (threadIdx.x >> 6);
        int lane = threadIdx.x & 63;
        const float* tr = tin + (size_t)row * kTC;
        float s0 = 0, s1 = 0, r0 = 0, r1 = 0;
        for (int k = lane; k < kTC; k += 64) {
            float u = fmaxf(tr[k], 0.f);
            s0 += u * fcw[k];
            s1 += u * fcw[512 + k];
            r0 += u * fcw[256 + k];
            r1 += u * fcw[768 + k];
        }
#pragma unroll
        for (int off = 32; off > 0; off >>= 1) {
            s0 += __shfl_down(s0, off); s1 += __shfl_down(s1, off);
            r0 += __shfl_down(r0, off); r1 += __shfl_down(r1, off);
        }
        if (lane == 0) lsr[row] = make_float4(s0 + fcb[0], s1 + fcb[1], r0, r1);
    }
}

// Ah_T[s][j][i] = (argmax==0) + (i==j); also accumulates degsum[j] = row-sum via atomics
__global__ __launch_bounds__(256) void k_adj(const float* __restrict__ gum, const float4* __restrict__ lsr,
                                             bf16_t* __restrict__ AT, float* __restrict__ degsum) {
    int s = blockIdx.z;
    int a0 = blockIdx.y * 64, b0 = blockIdx.x * 64;
    __shared__ bf16_t tile[64][72];
    int t = threadIdx.x;
    int lb = t & 63, ra = t >> 6;
    int b = b0 + lb;
    float4 pb = lsr[s * kN + b];
#pragma unroll 4
    for (int p = 0; p < 16; p++) {
        int a = a0 + p * 4 + ra;
        float4 qa = lsr[s * kN + a];
        float2 gv = *(const float2*)(gum + ((((size_t)s * kN + a) * kN + b) << 1));
        float u0 = fmaxf(gv.x, 1e-9f);
        float u1 = fmaxf(gv.y, 1e-9f);
        float g0 = -__logf(-__logf(u0));
        float g1 = -__logf(-__logf(u1));
        float v = ((qa.z + pb.x + g0) >= (qa.w + pb.y + g1)) ? 1.f : 0.f;
        if (a == b) v += 1.f;
        tile[lb][p * 4 + ra] = (bf16_t)v;
    }
    __syncthreads();
    int rj = t >> 3, li = (t & 7) * 8;
#pragma unroll
    for (int p = 0; p < 2; p++) {
        int j = p * 32 + rj;
        bf16x8 v = *(const bf16x8*)&tile[j][li];
        *(bf16x8*)(AT + ((size_t)s * kN + b0 + j) * kN + a0 + li) = v;
        float ps = 0;
#pragma unroll
        for (int q = 0; q < 8; q++) ps += (float)v[q];
        ps += __shfl_down(ps, 4);
        ps += __shfl_down(ps, 2);
        ps += __shfl_down(ps, 1);
        if ((t & 7) == 0) atomicAdd(degsum + s * kN + b0 + j, ps);
    }
}

// ---------------- bf16 NT GEMM: C(MxN) = A(MxK) * B(NxK)^T, 128x128 tile, BK=64 ----------------
// MODE 1: C = relu(rsqrt(deg[row])*acc + bias[col]). MODE 2: same, no relu.
template <int MODE>
__global__ __launch_bounds__(256) void k_gemm(const bf16_t* __restrict__ A, const bf16_t* __restrict__ B,
                                              bf16_t* __restrict__ C, int K, int lda, int ldb, int ldc,
                                              size_t sA, size_t sB, size_t sC,
                                              const float* __restrict__ degsum, const float* __restrict__ bias) {
    int m0 = blockIdx.x * 128, n0 = blockIdx.y * 128, s = blockIdx.z;
    A += sA * s; B += sB * s; C += sC * s;
    __shared__ bf16_t As[128][72], Bs[128][72];
    f32x4 acc[4][4] = {};
    int tid = threadIdx.x;
    int wave = tid >> 6, lane = tid & 63;
    int wm = (wave & 1) * 64, wn = (wave >> 1) * 64;
    int fm = lane & 15, fq = lane >> 4;
    int srow = tid >> 3, scol = (tid & 7) * 8;
    for (int kb = 0; kb < K; kb += 64) {
        __syncthreads();
#pragma unroll
        for (int p = 0; p < 4; p++) {
            int row = p * 32 + srow;
            *(uint4*)&As[row][scol] = *(const uint4*)(A + (size_t)(m0 + row) * lda + kb + scol);
            *(uint4*)&Bs[row][scol] = *(const uint4*)(B + (size_t)(n0 + row) * ldb + kb + scol);
        }
        __syncthreads();
#pragma unroll
        for (int kk = 0; kk < 2; kk++) {
            bf16x8 af[4], bfr[4];
#pragma unroll
            for (int i = 0; i < 4; i++) {
                af[i] = *(const bf16x8*)&As[wm + i * 16 + fm][kk * 32 + fq * 8];
                bfr[i] = *(const bf16x8*)&Bs[wn + i * 16 + fm][kk * 32 + fq * 8];
            }
#pragma unroll
            for (int i = 0; i < 4; i++)
#pragma unroll
                for (int j = 0; j < 4; j++)
                    acc[i][j] = __builtin_amdgcn_mfma_f32_16x16x32_bf16(af[i], bfr[j], acc[i][j], 0, 0, 0);
        }
    }
#pragma unroll
    for (int i = 0; i < 4; i++) {
#pragma unroll
        for (int r = 0; r < 4; r++) {
            int row = wm + i * 16 + fq * 4 + r;
            float sc = rsqrtf(degsum[(size_t)s * kN + m0 + row]);
#pragma unroll
            for (int j = 0; j < 4; j++) {
                int col = n0 + wn + j * 16 + fm;
                float v = sc * acc[i][j][r] + bias[col];
                if constexpr (MODE == 1) v = fmaxf(v, 0.f);
                C[(size_t)(m0 + row) * ldc + col] = (bf16_t)v;
            }
        }
    }
}

// ---- fused GEMM variants producing XW (plain) + ZT (scaled transpose) ----
// AF32: A operand is fp32, converted during staging. F = output cols (ld of XW).
// ZT[s][f][i] = rsqrt(deg[row]) * XW[row][f], row = s*512+i. DENSE_ROWS limits ZT writes.
template <bool AF32, int F, int DENSE_ROWS>
__global__ __launch_bounds__(256) void k_gemmT(const void* __restrict__ Ap, const bf16_t* __restrict__ B,
                                               bf16_t* __restrict__ XW, bf16_t* __restrict__ ZT, int K,
                                               const float* __restrict__ degsum) {
    int m0 = blockIdx.x * 128, n0 = blockIdx.y * 128;
    __shared__ __align__(16) bf16_t smem[2 * 128 * 72];  // As | Bs; reused as T[128][136]
    bf16_t* AsBase = smem;
    bf16_t* BsBase = smem + 128 * 72;
    f32x4 acc[4][4] = {};
    int tid = threadIdx.x;
    int wave = tid >> 6, lane = tid & 63;
    int wm = (wave & 1) * 64, wn = (wave >> 1) * 64;
    int fm = lane & 15, fq = lane >> 4;
    int srow = tid >> 3, scol = (tid & 7) * 8;
    for (int kb = 0; kb < K; kb += 64) {
        __syncthreads();
#pragma unroll
        for (int p = 0; p < 4; p++) {
            int row = p * 32 + srow;
            if constexpr (AF32) {
                const float* ap = (const float*)Ap + (size_t)(m0 + row) * K + kb + scol;
                float4 lo = *(const float4*)ap;
                float4 hi = *(const float4*)(ap + 4);
                bf16x8 o = {(bf16_t)lo.x, (bf16_t)lo.y, (bf16_t)lo.z, (bf16_t)lo.w,
                            (bf16_t)hi.x, (bf16_t)hi.y, (bf16_t)hi.z, (bf16_t)hi.w};
                *(bf16x8*)&AsBase[row * 72 + scol] = o;
            } else {
                *(uint4*)&AsBase[row * 72 + scol] =
                    *(const uint4*)((const bf16_t*)Ap + (size_t)(m0 + row) * K + kb + scol);
            }
            *(uint4*)&BsBase[row * 72 + scol] = *(const uint4*)(B + (size_t)(n0 + row) * K + kb + scol);
        }
        __syncthreads();
#pragma unroll
        for (int kk = 0; kk < 2; kk++) {
            bf16x8 af[4], bfr[4];
#pragma unroll
            for (int i = 0; i < 4; i++) {
                af[i] = *(const bf16x8*)&AsBase[(wm + i * 16 + fm) * 72 + kk * 32 + fq * 8];
                bfr[i] = *(const bf16x8*)&BsBase[(wn + i * 16 + fm) * 72 + kk * 32 + fq * 8];
            }
#pragma unroll
            for (int i = 0; i < 4; i++)
#pragma unroll
                for (int j = 0; j < 4; j++)
                    acc[i][j] = __builtin_amdgcn_mfma_f32_16x16x32_bf16(af[i], bfr[j], acc[i][j], 0, 0, 0);
        }
    }
    // write XW (unscaled) + stage scaled values into LDS transposed
    bool doT = (m0 < DENSE_ROWS);
    __syncthreads();  // all ds_reads of the K-loop complete before LDS reuse
#pragma unroll
    for (int i = 0; i < 4; i++) {
#pragma unroll
        for (int r = 0; r < 4; r++) {
            int row = wm + i * 16 + fq * 4 + r;
            float sc = doT ? rsqrtf(degsum[m0 + row]) : 0.f;
#pragma unroll
            for (int j = 0; j < 4; j++) {
                int col = wn + j * 16 + fm;
                float v = acc[i][j][r];
                XW[(size_t)(m0 + row) * F + n0 + col] = (bf16_t)v;
                if (doT) smem[col * 136 + row] = (bf16_t)(sc * v);
            }
        }
    }
    if (doT) {
        __syncthreads();
        int fr = tid >> 1, hi = (tid & 1) * 64;
        bf16_t* zrow = ZT + ((size_t)(m0 >> 9) * F + n0 + fr) * kN + (m0 & 511) + hi;
#pragma unroll
        for (int q = 0; q < 8; q++)
            *(bf16x8*)(zrow + q * 8) = *(const bf16x8*)&smem[fr * 136 + hi + q * 8];
    }
}

// ---------------- sparse path ----------------

__global__ __launch_bounds__(256) void k_hist(const int* __restrict__ col, int* __restrict__ counts) {
    int e = blockIdx.x * 256 + threadIdx.x;
    if (e < kE) atomicAdd(&counts[col[e]], 1);
}

// single block, 1024 threads; padded LDS indexing (j + j/32) to avoid bank conflicts
__global__ __launch_bounds__(1024) void k_scan(const int* __restrict__ counts, int* __restrict__ offsets,
                                               int* __restrict__ cursor, float* __restrict__ dis_s) {
    __shared__ int ldc_[16896];
    __shared__ int sums[1024];
    int t = threadIdx.x;
#define IDX(j) ((j) + ((j) >> 5))
    for (int i = 0; i < 16; i++) {
        int g = i * 1024 + t;
        int c = counts[g];
        ldc_[IDX(g)] = c;
        dis_s[g] = rsqrtf((float)(c + 1));  // deg includes self loop
    }
    __syncthreads();
    int s = 0;
    for (int i = 0; i < 16; i++) s += ldc_[IDX(t * 16 + i)];
    sums[t] = s;
    __syncthreads();
    for (int off = 1; off < 1024; off <<= 1) {
        int y = (t >= off) ? sums[t - off] : 0;
        __syncthreads();
        sums[t] += y;
        __syncthreads();
    }
    int run = sums[t] - s;  // exclusive prefix
    for (int i = 0; i < 16; i++) {
        int j = t * 16 + i;
        int c = ldc_[IDX(j)];
        ldc_[IDX(j)] = run;
        run += c;
    }
    __syncthreads();
    for (int i = 0; i < 16; i++) {
        int g = i * 1024 + t;
        int o = ldc_[IDX(g)];
        offsets[g] = o;
        cursor[g] = o;
    }
#undef IDX
}

__global__ __launch_bounds__(256) void k_fill(const int* __restrict__ row, const int* __restrict__ col,
                                              int* __restrict__ cursor, int* __restrict__ list) {
    int e = blockIdx.x * 256 + threadIdx.x;
    if (e < kE) {
        int p = atomicAdd(&cursor[col[e]], 1);
        list[p] = row[e];
    }
}

// out[j,f8..f8+7] via bf16x8 gathers; OUT row j, ld 256
template <int F, bool RELU>
__global__ __launch_bounds__(256) void k_sagg(const bf16_t* __restrict__ XW, int rowOffIn,
                                              const int* __restrict__ list, const int* __restrict__ offsets,
                                              const int* __restrict__ counts, const float* __restrict__ dis_s,
                                              const float* __restrict__ bias, bf16_t* __restrict__ OUT,
                                              int outColOff) {
    constexpr int TPR = F / 8;        // threads per row
    constexpr int RPB = 256 / TPR;    // rows per block
    int j = blockIdx.x * RPB + threadIdx.x / TPR;
    int f8 = (threadIdx.x % TPR) * 8;
    float dj = dis_s[j];
    const bf16_t* base = XW + (size_t)rowOffIn * F;
    float acc[8];
    {
        bf16x8 v = *(const bf16x8*)(base + (size_t)j * F + f8);
#pragma unroll
        for (int q = 0; q < 8; q++) acc[q] = dj * (float)v[q];
    }
    int off = offsets[j], cnt = counts[j];
    int e = 0;
    for (; e + 8 <= cnt; e += 8) {
        int r[8];
#pragma unroll
        for (int q = 0; q < 8; q++) r[q] = list[off + e + q];
        float d[8];
#pragma unroll
        for (int q = 0; q < 8; q++) d[q] = dis_s[r[q]];
        bf16x8 v0 = *(const bf16x8*)(base + (size_t)r[0] * F + f8);
        bf16x8 v1 = *(const bf16x8*)(base + (size_t)r[1] * F + f8);
        bf16x8 v2 = *(const bf16x8*)(base + (size_t)r[2] * F + f8);
        bf16x8 v3 = *(const bf16x8*)(base + (size_t)r[3] * F + f8);
        bf16x8 v4 = *(const bf16x8*)(base + (size_t)r[4] * F + f8);
        bf16x8 v5 = *(const bf16x8*)(base + (size_t)r[5] * F + f8);
        bf16x8 v6 = *(const bf16x8*)(base + (size_t)r[6] * F + f8);
        bf16x8 v7 = *(const bf16x8*)(base + (size_t)r[7] * F + f8);
#pragma unroll
        for (int q = 0; q < 8; q++)
            acc[q] += ((d[0] * (float)v0[q] + d[1] * (float)v1[q]) + (d[2] * (float)v2[q] + d[3] * (float)v3[q])) +
                      ((d[4] * (float)v4[q] + d[5] * (float)v5[q]) + (d[6] * (float)v6[q] + d[7] * (float)v7[q]));
    }
    for (; e + 4 <= cnt; e += 4) {
        int r0 = list[off + e], r1 = list[off + e + 1], r2 = list[off + e + 2], r3 = list[off + e + 3];
        float d0 = dis_s[r0], d1 = dis_s[r1], d2 = dis_s[r2], d3 = dis_s[r3];
        bf16x8 v0 = *(const bf16x8*)(base + (size_t)r0 * F + f8);
        bf16x8 v1 = *(const bf16x8*)(base + (size_t)r1 * F + f8);
        bf16x8 v2 = *(const bf16x8*)(base + (size_t)r2 * F + f8);
        bf16x8 v3 = *(const bf16x8*)(base + (size_t)r3 * F + f8);
#pragma unroll
        for (int q = 0; q < 8; q++)
            acc[q] += (d0 * (float)v0[q] + d1 * (float)v1[q]) + (d2 * (float)v2[q] + d3 * (float)v3[q]);
    }
    for (; e < cnt; e++) {
        int r = list[off + e];
        float d = dis_s[r];
        bf16x8 v = *(const bf16x8*)(base + (size_t)r * F + f8);
#pragma unroll
        for (int q = 0; q < 8; q++) acc[q] += d * (float)v[q];
    }
    bf16x8 o;
#pragma unroll
    for (int q = 0; q < 8; q++) {
        float v = dj * acc[q] + bias[f8 + q];
        if (RELU) v = fmaxf(v, 0.f);
        o[q] = (bf16_t)v;
    }
    *(bf16x8*)(OUT + (size_t)j * 256 + outColOff + f8) = o;
}

// ---------------- FCN head ----------------
// register-direct split-K MFMA: 256 blocks, block b covers K chunk [b*512, b*512+512).
__global__ __launch_bounds__(256) void k_fcn1(const bf16_t* __restrict__ EMB, const float* __restrict__ W1,
                                              float* __restrict__ partials) {
    int tid = threadIdx.x, wave = tid >> 6, lane = tid & 63;
    int fm = lane & 15, fq = lane >> 4;
    int kb0 = blockIdx.x * 512;
    f32x4 acc[2][4] = {};
#pragma unroll 4
    for (int ks = 0; ks < 512; ks += 32) {
        int k = kb0 + ks + fq * 8;
        bf16x8 a0 = *(const bf16x8*)(EMB + (size_t)fm * 131072 + k);
        bf16x8 a1 = *(const bf16x8*)(EMB + (size_t)(16 + fm) * 131072 + k);
        bf16x8 bfr[4];
#pragma unroll
        for (int j = 0; j < 4; j++) {
            int n = wave * 64 + j * 16 + fm;
            const float* p = W1 + (size_t)n * 131072 + k;
            float4 lo = *(const float4*)p;
            float4 hi = *(const float4*)(p + 4);
            bf16x8 b = {(bf16_t)lo.x, (bf16_t)lo.y, (bf16_t)lo.z, (bf16_t)lo.w,
                        (bf16_t)hi.x, (bf16_t)hi.y, (bf16_t)hi.z, (bf16_t)hi.w};
            bfr[j] = b;
        }
#pragma unroll
        for (int j = 0; j < 4; j++) {
            acc[0][j] = __builtin_amdgcn_mfma_f32_16x16x32_bf16(a0, bfr[j], acc[0][j], 0, 0, 0);
            acc[1][j] = __builtin_amdgcn_mfma_f32_16x16x32_bf16(a1, bfr[j], acc[1][j], 0, 0, 0);
        }
    }
    float* P = partials + (size_t)blockIdx.x * 8192;
#pragma unroll
    for (int i = 0; i < 2; i++)
#pragma unroll
        for (int j = 0; j < 4; j++)
#pragma unroll
            for (int r = 0; r < 4; r++)
                P[(size_t)(i * 16 + fq * 4 + r) * 256 + wave * 64 + j * 16 + fm] = acc[i][j][r];
}

// reduce 256 partials -> h1pre[8192] (coalesced: thread e strides the slice dim)
__global__ __launch_bounds__(256) void k_reduce(const float* __restrict__ partials, float* __restrict__ h1pre) {
    int e = blockIdx.x * 256 + threadIdx.x;
    float s = 0;
#pragma unroll 8
    for (int i = 0; i < 256; i++) s += partials[(size_t)i * 8192 + e];
    h1pre[e] = s;
}

// final: h1 = leaky(h1pre + b1); h2 = leaky(h1@W2^T+b2); out = h2@W3^T+b3
__global__ __launch_bounds__(256) void k_head(const float* __restrict__ h1pre, const float* __restrict__ b1,
                                              const float* __restrict__ W2, const float* __restrict__ b2,
                                              const float* __restrict__ W3, const float* __restrict__ b3,
                                              float* __restrict__ out) {
    __shared__ float h1s[32][256];
    __shared__ float h2s[32][32];
    int t = threadIdx.x;
    for (int i = 0; i < 32; i++) {
        float s = h1pre[i * 256 + t] + b1[t];
        h1s[i][t] = (s > 0.f) ? s : 0.2f * s;
    }
    __syncthreads();
    for (int p = 0; p < 4; p++) {
        int id = p * 256 + t, si = id >> 5, o2 = id & 31;
        float s = 0;
        for (int k = 0; k < 256; k++) s += h1s[si][k] * W2[o2 * 256 + k];
        s += b2[o2];
        h2s[si][o2] = (s > 0.f) ? s : 0.2f * s;
    }
    __syncthreads();
    if (t < 64) {
        int si = t >> 1, o3 = t & 1;
        float s = 0;
#pragma unroll
        for (int k = 0; k < 32; k++) s += h2s[si][k] * W3[o3 * 32 + k];
        out[si * 2 + o3] = s + b3[o3];
    }
}

// ---------------- launcher ----------------

extern "C" void kernel_launch(void* const* d_in, const int* in_sizes, int n_in,
                              void* d_out, int out_size, void* d_ws, size_t ws_size,
                              hipStream_t stream) {
    const float* x = (const float*)d_in[0];
    const float* t = (const float*)d_in[1];
    const float* gum = (const float*)d_in[2];
    const int* eidx = (const int*)d_in[3];
    const float* c1w = (const float*)d_in[4];
    const float* c1b = (const float*)d_in[5];
    const float* c2w = (const float*)d_in[6];
    const float* c2b = (const float*)d_in[7];
    const float* fcw = (const float*)d_in[8];
    const float* fcb = (const float*)d_in[9];
    const float* w1 = (const float*)d_in[10];
    const float* b1 = (const float*)d_in[11];
    const float* w2 = (const float*)d_in[12];
    const float* b2 = (const float*)d_in[13];
    const float* w3 = (const float*)d_in[14];
    const float* b3 = (const float*)d_in[15];
    float* out = (float*)d_out;
    (void)in_sizes; (void)n_in; (void)out_size; (void)ws_size;

    char* ws = (char*)d_ws;
    size_t off = 0;
    auto alloc = [&](size_t bytes) -> char* {
        char* p = ws + off;
        off += (bytes + 255) & ~size_t(255);
        return p;
    };
    bf16_t* c1wb = (bf16_t*)alloc((size_t)256 * 512 * 2);
    bf16_t* c2wb = (bf16_t*)alloc((size_t)128 * 256 * 2);
    float4* lsr = (float4*)alloc((size_t)kNTOT * 16);
    bf16_t* AT = (bf16_t*)alloc((size_t)kBZ * kN * kN * 2);          // 16.8 MB
    float* degsum = (float*)alloc((size_t)kNTOT * 4);
    bf16_t* XW1_EMB = (bf16_t*)alloc((size_t)kNTOT * 256 * 2);       // 8.4 MB (XW1 then EMB)
    bf16_t* Z1T = (bf16_t*)alloc((size_t)kBZ * 256 * 512 * 2);       // 8.4 MB
    bf16_t* H = (bf16_t*)alloc((size_t)32768 * 256 * 2);             // 16.8 MB
    bf16_t* XW2 = (bf16_t*)alloc((size_t)32768 * 128 * 2);           // 8.4 MB
    bf16_t* Z2T = (bf16_t*)alloc((size_t)kBZ * 128 * 512 * 2);       // 4.2 MB
    int* counts = (int*)alloc((size_t)kNTOT * 4);
    int* offsets = (int*)alloc((size_t)kNTOT * 4);
    int* cursor = (int*)alloc((size_t)kNTOT * 4);
    float* diss = (float*)alloc((size_t)kNTOT * 4);
    int* list = (int*)alloc((size_t)kE * 4);
    float* partials = (float*)alloc((size_t)256 * 8192 * 4);         // 8.4 MB
    float* h1pre = (float*)alloc((size_t)8192 * 4);

    bf16_t* XW1 = XW1_EMB;
    bf16_t* EMB = XW1_EMB;  // EMB written only after XW1's last read (sparse L1)

    // front: weight cvt + zero counts/degsum/h1acc + lsr
    k_front<<<4296, 256, 0, stream>>>(c1w, c2w, c1wb, c2wb, counts, degsum, h1pre, t, fcw, fcb, lsr);
    k_adj<<<dim3(8, 8, 32), 256, 0, stream>>>(gum, lsr, AT, degsum);
    // sparse CSR build
    k_hist<<<2048, 256, 0, stream>>>(eidx + kE, counts);
    k_scan<<<1, 1024, 0, stream>>>(counts, offsets, cursor, diss);
    k_fill<<<2048, 256, 0, stream>>>(eidx, eidx + kE, cursor, list);
    // XW1 = x @ conv1_w^T (fp32 A converted in-staging) + Z1T scaled transpose
    k_gemmT<true, 256, kNTOT><<<dim3(128, 2, 1), 256, 0, stream>>>(x, c1wb, XW1, Z1T, 512, degsum);
    // dense layer 1: H[dense] = relu(dis*(AT@Z1) + b1)
    k_gemm<1><<<dim3(4, 2, 32), 256, 0, stream>>>(AT, Z1T, H, 512, 512, 512, 256,
                                                  (size_t)512 * 512, (size_t)256 * 512, (size_t)512 * 256,
                                                  degsum, c1b);
    // sparse layer 1 -> H rows 16384..
    k_sagg<256, true><<<2048, 256, 0, stream>>>(XW1, 0, list, offsets, counts, diss, c1b,
                                                H + (size_t)16384 * 256, 0);
    // stacked layer-2 matmul: XW2 = H @ conv2_w^T (+ Z2T for dense rows)
    k_gemmT<false, 128, kNTOT><<<dim3(256, 1, 1), 256, 0, stream>>>(H, c2wb, XW2, Z2T, 256, degsum);
    // dense layer 2 -> EMB cols 0..127
    k_gemm<2><<<dim3(4, 1, 32), 256, 0, stream>>>(AT, Z2T, EMB, 512, 512, 512, 256,
                                                  (size_t)512 * 512, (size_t)128 * 512, (size_t)512 * 256,
                                                  degsum, c2b);
    // sparse layer 2 -> EMB cols 128..255
    k_sagg<128, false><<<1024, 256, 0, stream>>>(XW2, 16384, list, offsets, counts, diss, c2b, EMB, 128);
    // FCN head
    k_fcn1<<<256, 256, 0, stream>>>(EMB, w1, partials);
    k_reduce<<<32, 256, 0, stream>>>(partials, h1pre);
    k_head<<<1, 256, 0, stream>>>(h1pre, b1, w2, b2, w3, b3, out);
}

// Round 2
// 506.106 us; speedup vs baseline: 1.0220x; 1.0037x over previous
//
#include <hip/hip_runtime.h>
#include <hip/hip_bf16.h>

typedef __bf16 bf16_t;
typedef __bf16 bf16x8 __attribute__((ext_vector_type(8)));
typedef __bf16 bf16x4 __attribute__((ext_vector_type(4)));
typedef float f32x4 __attribute__((ext_vector_type(4)));

constexpr int kN = 512;       // nodes per sample
constexpr int kBZ = 32;       // batch
constexpr int kTC = 256;
constexpr int kE = 524288;
constexpr int kNTOT = 16384;  // kBZ*kN

// ---- async global->LDS helpers (16B, XOR chunk swizzle, rule #21 both-sides) ----
__device__ __forceinline__ void gll16(const bf16_t* g, bf16_t* l) {
    __builtin_amdgcn_global_load_lds((const __attribute__((address_space(1))) void*)g,
                                     (__attribute__((address_space(3))) void*)l, 16, 0, 0);
}

// stage a 128x64 bf16 tile (row-major src, row stride ld elems) into linear LDS [128][64].
// 16B chunk c of row r stored at slot (c ^ (r&7)). 4 global_load_lds per wave (8 rows each).
__device__ __forceinline__ void stage128x64(const bf16_t* __restrict__ src, int ld,
                                            bf16_t* lds, int wave, int lane) {
#pragma unroll
    for (int i = 0; i < 4; i++) {
        int r0 = (wave * 4 + i) * 8;
        int r = r0 + (lane >> 3);
        int c = (lane & 7) ^ (r & 7);
        gll16(src + (size_t)r * ld + c * 8, lds + r0 * 64);
    }
}

// read 16B fragment (8 bf16) at (row, 16B-chunk cc) from swizzled [128][64] tile
__device__ __forceinline__ bf16x8 rdfrag(const bf16_t* lds, int row, int cc) {
    return *(const bf16x8*)(lds + row * 64 + ((cc ^ (row & 7)) * 8));
}

// ---------------- front: weight convert + zero-init + lsr ----------------
// blocks [0,192): convert/zero. quads: c1w (32768), c2w (8192), counts zero (4096 int4),
//                 degsum zero (4096 float4)
// blocks [192,4288): lsr body. P0=ls0+b0, P1=ls1+b1, Q0=lr0, Q1=lr1 per row (u = relu(t))
__global__ __launch_bounds__(256) void k_front(const float* __restrict__ c1w, const float* __restrict__ c2w,
                                               bf16_t* __restrict__ c1b, bf16_t* __restrict__ c2b,
                                               int* __restrict__ counts, float* __restrict__ degsum,
                                               const float* __restrict__ tin, const float* __restrict__ fcw,
                                               const float* __restrict__ fcb, float4* __restrict__ lsr) {
    int b = blockIdx.x;
    if (b < 192) {
        int i = b * 256 + threadIdx.x;
        const int n0 = 32768, n1 = n0 + 8192, n2 = n1 + 4096, n3 = n2 + 4096;
        if (i < n0) {
            float4 v = ((const float4*)c1w)[i];
            bf16x4 o = {(bf16_t)v.x, (bf16_t)v.y, (bf16_t)v.z, (bf16_t)v.w};
            ((bf16x4*)c1b)[i] = o;
        } else if (i < n1) {
            int j = i - n0;
            float4 v = ((const float4*)c2w)[j];
            bf16x4 o = {(bf16_t)v.x, (bf16_t)v.y, (bf16_t)v.z, (bf16_t)v.w};
            ((bf16x4*)c2b)[j] = o;
        } else if (i < n2) {
            ((int4*)counts)[i - n1] = make_int4(0, 0, 0, 0);
        } else if (i < n3) {
            ((float4*)degsum)[i - n2] = make_float4(0.f, 0.f, 0.f, 0.f);
        }
    } else {
        int row = (b - 192) * 4 + (threadIdx.x >> 6);
        int lane = threadIdx.x & 63;
        const float* tr = tin + (size_t)row * kTC;
        float s0 = 0, s1 = 0, r0 = 0, r1 = 0;
        for (int k = lane; k < kTC; k += 64) {
            float u = fmaxf(tr[k], 0.f);
            s0 += u * fcw[k];
            s1 += u * fcw[512 + k];
            r0 += u * fcw[256 + k];
            r1 += u * fcw[768 + k];
        }
#pragma unroll
        for (int off = 32; off > 0; off >>= 1) {
            s0 += __shfl_down(s0, off); s1 += __shfl_down(s1, off);
            r0 += __shfl_down(r0, off); r1 += __shfl_down(r1, off);
        }
        if (lane == 0) lsr[row] = make_float4(s0 + fcb[0], s1 + fcb[1], r0, r1);
    }
}

// Ah_T[s][j][i] = (argmax==0) + (i==j); also accumulates degsum[j] = row-sum via atomics
__global__ __launch_bounds__(256) void k_adj(const float* __restrict__ gum, const float4* __restrict__ lsr,
                                             bf16_t* __restrict__ AT, float* __restrict__ degsum) {
    int s = blockIdx.z;
    int a0 = blockIdx.y * 64, b0 = blockIdx.x * 64;
    __shared__ bf16_t tile[64][72];
    int t = threadIdx.x;
    int lb = t & 63, ra = t >> 6;
    int b = b0 + lb;
    float4 pb = lsr[s * kN + b];
#pragma unroll 4
    for (int p = 0; p < 16; p++) {
        int a = a0 + p * 4 + ra;
        float4 qa = lsr[s * kN + a];
        float2 gv = *(const float2*)(gum + ((((size_t)s * kN + a) * kN + b) << 1));
        float u0 = fmaxf(gv.x, 1e-9f);
        float u1 = fmaxf(gv.y, 1e-9f);
        float g0 = -__logf(-__logf(u0));
        float g1 = -__logf(-__logf(u1));
        float v = ((qa.z + pb.x + g0) >= (qa.w + pb.y + g1)) ? 1.f : 0.f;
        if (a == b) v += 1.f;
        tile[lb][p * 4 + ra] = (bf16_t)v;
    }
    __syncthreads();
    int rj = t >> 3, li = (t & 7) * 8;
#pragma unroll
    for (int p = 0; p < 2; p++) {
        int j = p * 32 + rj;
        bf16x8 v = *(const bf16x8*)&tile[j][li];
        *(bf16x8*)(AT + ((size_t)s * kN + b0 + j) * kN + a0 + li) = v;
        float ps = 0;
#pragma unroll
        for (int q = 0; q < 8; q++) ps += (float)v[q];
        ps += __shfl_down(ps, 4);
        ps += __shfl_down(ps, 2);
        ps += __shfl_down(ps, 1);
        if ((t & 7) == 0) atomicAdd(degsum + s * kN + b0 + j, ps);
    }
}

// ---------------- bf16 NT GEMM: C(MxN) = A(MxK) * B(NxK)^T, 128x128 tile, BK=64 ----------------
// 2-phase pipeline: double-buffered LDS, global_load_lds staging of tile t+1 overlaps MFMA of t.
// MODE 1: C = relu(rsqrt(deg[row])*acc + bias[col]). MODE 2: same, no relu.
template <int MODE>
__global__ __launch_bounds__(256) void k_gemm(const bf16_t* __restrict__ A, const bf16_t* __restrict__ B,
                                              bf16_t* __restrict__ C, int K, int lda, int ldb, int ldc,
                                              size_t sA, size_t sB, size_t sC,
                                              const float* __restrict__ degsum, const float* __restrict__ bias) {
    int m0 = blockIdx.x * 128, n0 = blockIdx.y * 128, s = blockIdx.z;
    const bf16_t* Ab = A + sA * s + (size_t)m0 * lda;
    const bf16_t* Bb = B + sB * s + (size_t)n0 * ldb;
    C += sC * s;
    __shared__ __align__(16) bf16_t As[2][128 * 64], Bs[2][128 * 64];
    f32x4 acc[4][4] = {};
    int tid = threadIdx.x;
    int wave = tid >> 6, lane = tid & 63;
    int wm = (wave & 1) * 64, wn = (wave >> 1) * 64;
    int fm = lane & 15, fq = lane >> 4;
    stage128x64(Ab, lda, As[0], wave, lane);
    stage128x64(Bb, ldb, Bs[0], wave, lane);
    int cur = 0;
    for (int kb = 0;;) {
        int kn = kb + 64;
        __syncthreads();  // drains vmcnt: buf[cur] staged; buf[cur^1] reads (prev iter) done
        if (kn < K) {
            stage128x64(Ab + kn, lda, As[cur ^ 1], wave, lane);
            stage128x64(Bb + kn, ldb, Bs[cur ^ 1], wave, lane);
        }
#pragma unroll
        for (int kk = 0; kk < 2; kk++) {
            bf16x8 af[4], bfr[4];
#pragma unroll
            for (int i = 0; i < 4; i++) {
                af[i] = rdfrag(As[cur], wm + i * 16 + fm, kk * 4 + fq);
                bfr[i] = rdfrag(Bs[cur], wn + i * 16 + fm, kk * 4 + fq);
            }
#pragma unroll
            for (int i = 0; i < 4; i++)
#pragma unroll
                for (int j = 0; j < 4; j++)
                    acc[i][j] = __builtin_amdgcn_mfma_f32_16x16x32_bf16(af[i], bfr[j], acc[i][j], 0, 0, 0);
        }
        kb = kn;
        if (kb >= K) break;
        cur ^= 1;
    }
#pragma unroll
    for (int i = 0; i < 4; i++) {
#pragma unroll
        for (int r = 0; r < 4; r++) {
            int row = wm + i * 16 + fq * 4 + r;
            float sc = rsqrtf(degsum[(size_t)s * kN + m0 + row]);
#pragma unroll
            for (int j = 0; j < 4; j++) {
                int col = n0 + wn + j * 16 + fm;
                float v = sc * acc[i][j][r] + bias[col];
                if constexpr (MODE == 1) v = fmaxf(v, 0.f);
                C[(size_t)(m0 + row) * ldc + col] = (bf16_t)v;
            }
        }
    }
}

// ---- fused GEMM variants producing XW (plain) + ZT (scaled transpose) ----
// AF32: A operand is fp32, reg-staged (issue-early / write-late, T14). F = output cols.
// ZT[s][f][i] = rsqrt(deg[row]) * XW[row][f], row = s*512+i. DENSE_ROWS limits ZT writes.
template <bool AF32, int F, int DENSE_ROWS>
__global__ __launch_bounds__(256) void k_gemmT(const void* __restrict__ Ap, const bf16_t* __restrict__ B,
                                               bf16_t* __restrict__ XW, bf16_t* __restrict__ ZT, int K,
                                               const float* __restrict__ degsum) {
    int m0 = blockIdx.x * 128, n0 = blockIdx.y * 128;
    constexpr int AST = AF32 ? 9216 : 8192;  // per-buffer A elems (padded [128][72] when fp32-staged)
    __shared__ __align__(16) bf16_t smem[2 * AST + 2 * 8192];
    bf16_t* A0 = smem;
    bf16_t* A1 = smem + AST;
    bf16_t* B0 = smem + 2 * AST;
    bf16_t* B1 = smem + 2 * AST + 8192;
    f32x4 acc[4][4] = {};
    int tid = threadIdx.x;
    int wave = tid >> 6, lane = tid & 63;
    int wm = (wave & 1) * 64, wn = (wave >> 1) * 64;
    int fm = lane & 15, fq = lane >> 4;
    int srow = tid >> 3, scol = (tid & 7) * 8;
    const float* Af = (const float*)Ap;
    const bf16_t* Abf = (const bf16_t*)Ap;
    // prologue: stage tile 0
    if constexpr (AF32) {
#pragma unroll
        for (int p = 0; p < 4; p++) {
            int row = p * 32 + srow;
            const float* ap = Af + (size_t)(m0 + row) * K + scol;
            float4 lo = *(const float4*)ap, hi = *(const float4*)(ap + 4);
            bf16x8 o = {(bf16_t)lo.x, (bf16_t)lo.y, (bf16_t)lo.z, (bf16_t)lo.w,
                        (bf16_t)hi.x, (bf16_t)hi.y, (bf16_t)hi.z, (bf16_t)hi.w};
            *(bf16x8*)&A0[row * 72 + scol] = o;
        }
    } else {
        stage128x64(Abf + (size_t)m0 * K, K, A0, wave, lane);
    }
    stage128x64(B + (size_t)n0 * K, K, B0, wave, lane);
    int cur = 0;
    for (int kb = 0;;) {
        int kn = kb + 64;
        bool more = kn < K;
        bf16_t* Ac = cur ? A1 : A0;
        bf16_t* An = cur ? A0 : A1;
        bf16_t* Bc = cur ? B1 : B0;
        bf16_t* Bn = cur ? B0 : B1;
        float4 plo[4], phi[4];
        __syncthreads();
        if (more) {
            if constexpr (AF32) {
#pragma unroll
                for (int p = 0; p < 4; p++) {  // issue-early: loads fly during MFMA below
                    int row = p * 32 + srow;
                    const float* ap = Af + (size_t)(m0 + row) * K + kn + scol;
                    plo[p] = *(const float4*)ap;
                    phi[p] = *(const float4*)(ap + 4);
                }
            } else {
                stage128x64(Abf + (size_t)m0 * K + kn, K, An, wave, lane);
            }
            stage128x64(B + (size_t)n0 * K + kn, K, Bn, wave, lane);
        }
#pragma unroll
        for (int kk = 0; kk < 2; kk++) {
            bf16x8 af[4], bfr[4];
#pragma unroll
            for (int i = 0; i < 4; i++) {
                if constexpr (AF32)
                    af[i] = *(const bf16x8*)&Ac[(wm + i * 16 + fm) * 72 + kk * 32 + fq * 8];
                else
                    af[i] = rdfrag(Ac, wm + i * 16 + fm, kk * 4 + fq);
                bfr[i] = rdfrag(Bc, wn + i * 16 + fm, kk * 4 + fq);
            }
#pragma unroll
            for (int i = 0; i < 4; i++)
#pragma unroll
                for (int j = 0; j < 4; j++)
                    acc[i][j] = __builtin_amdgcn_mfma_f32_16x16x32_bf16(af[i], bfr[j], acc[i][j], 0, 0, 0);
        }
        if constexpr (AF32) {
            if (more) {  // write-late: cvt + ds_write after compute
#pragma unroll
                for (int p = 0; p < 4; p++) {
                    int row = p * 32 + srow;
                    bf16x8 o = {(bf16_t)plo[p].x, (bf16_t)plo[p].y, (bf16_t)plo[p].z, (bf16_t)plo[p].w,
                                (bf16_t)phi[p].x, (bf16_t)phi[p].y, (bf16_t)phi[p].z, (bf16_t)phi[p].w};
                    *(bf16x8*)&An[row * 72 + scol] = o;
                }
            }
        }
        kb = kn;
        if (kb >= K) break;
        cur ^= 1;
    }
    // write XW (unscaled) + stage scaled values into LDS transposed
    bool doT = (m0 < DENSE_ROWS);
    __syncthreads();  // all LDS ops of the K-loop complete before reuse as T[128][136]
#pragma unroll
    for (int i = 0; i < 4; i++) {
#pragma unroll
        for (int r = 0; r < 4; r++) {
            int row = wm + i * 16 + fq * 4 + r;
            float sc = doT ? rsqrtf(degsum[m0 + row]) : 0.f;
#pragma unroll
            for (int j = 0; j < 4; j++) {
                int col = wn + j * 16 + fm;
                float v = acc[i][j][r];
                XW[(size_t)(m0 + row) * F + n0 + col] = (bf16_t)v;
                if (doT) smem[col * 136 + row] = (bf16_t)(sc * v);
            }
        }
    }
    if (doT) {
        __syncthreads();
        int fr = tid >> 1, hi = (tid & 1) * 64;
        bf16_t* zrow = ZT + ((size_t)(m0 >> 9) * F + n0 + fr) * kN + (m0 & 511) + hi;
#pragma unroll
        for (int q = 0; q < 8; q++)
            *(bf16x8*)(zrow + q * 8) = *(const bf16x8*)&smem[fr * 136 + hi + q * 8];
    }
}

// ---------------- sparse path ----------------

__global__ __launch_bounds__(256) void k_hist(const int* __restrict__ col, int* __restrict__ counts) {
    int e = blockIdx.x * 256 + threadIdx.x;
    if (e < kE) atomicAdd(&counts[col[e]], 1);
}

// single block, 1024 threads; padded LDS indexing (j + j/32) to avoid bank conflicts
__global__ __launch_bounds__(1024) void k_scan(const int* __restrict__ counts, int* __restrict__ offsets,
                                               int* __restrict__ cursor, float* __restrict__ dis_s) {
    __shared__ int ldc_[16896];
    __shared__ int sums[1024];
    int t = threadIdx.x;
#define IDX(j) ((j) + ((j) >> 5))
    for (int i = 0; i < 16; i++) {
        int g = i * 1024 + t;
        int c = counts[g];
        ldc_[IDX(g)] = c;
        dis_s[g] = rsqrtf((float)(c + 1));  // deg includes self loop
    }
    __syncthreads();
    int s = 0;
    for (int i = 0; i < 16; i++) s += ldc_[IDX(t * 16 + i)];
    sums[t] = s;
    __syncthreads();
    for (int off = 1; off < 1024; off <<= 1) {
        int y = (t >= off) ? sums[t - off] : 0;
        __syncthreads();
        sums[t] += y;
        __syncthreads();
    }
    int run = sums[t] - s;  // exclusive prefix
    for (int i = 0; i < 16; i++) {
        int j = t * 16 + i;
        int c = ldc_[IDX(j)];
        ldc_[IDX(j)] = run;
        run += c;
    }
    __syncthreads();
    for (int i = 0; i < 16; i++) {
        int g = i * 1024 + t;
        int o = ldc_[IDX(g)];
        offsets[g] = o;
        cursor[g] = o;
    }
#undef IDX
}

__global__ __launch_bounds__(256) void k_fill(const int* __restrict__ row, const int* __restrict__ col,
                                              int* __restrict__ cursor, int* __restrict__ list) {
    int e = blockIdx.x * 256 + threadIdx.x;
    if (e < kE) {
        int p = atomicAdd(&cursor[col[e]], 1);
        list[p] = row[e];
    }
}

// out[j,f8..f8+7] via bf16x8 gathers; OUT row j, ld 256. List-prefetch software pipeline.
template <int F, bool RELU>
__global__ __launch_bounds__(256) void k_sagg(const bf16_t* __restrict__ XW, int rowOffIn,
                                              const int* __restrict__ list, const int* __restrict__ offsets,
                                              const int* __restrict__ counts, const float* __restrict__ dis_s,
                                              const float* __restrict__ bias, bf16_t* __restrict__ OUT,
                                              int outColOff) {
    constexpr int TPR = F / 8;        // threads per row
    constexpr int RPB = 256 / TPR;    // rows per block
    int j = blockIdx.x * RPB + threadIdx.x / TPR;
    int f8 = (threadIdx.x % TPR) * 8;
    float dj = dis_s[j];
    const bf16_t* base = XW + (size_t)rowOffIn * F;
    float acc[8];
    {
        bf16x8 v = *(const bf16x8*)(base + (size_t)j * F + f8);
#pragma unroll
        for (int q = 0; q < 8; q++) acc[q] = dj * (float)v[q];
    }
    int off = offsets[j], cnt = counts[j];
    int e = 0;
    int nb = cnt & ~7;
    if (nb) {
        int r[8];
#pragma unroll
        for (int q = 0; q < 8; q++) r[q] = list[off + q];
        while (true) {
            int en = e + 8;
            bool more = en < nb;
            int rn[8];
            if (more) {
#pragma unroll
                for (int q = 0; q < 8; q++) rn[q] = list[off + en + q];
            }
            float d[8];
#pragma unroll
            for (int q = 0; q < 8; q++) d[q] = dis_s[r[q]];
            bf16x8 v0 = *(const bf16x8*)(base + (size_t)r[0] * F + f8);
            bf16x8 v1 = *(const bf16x8*)(base + (size_t)r[1] * F + f8);
            bf16x8 v2 = *(const bf16x8*)(base + (size_t)r[2] * F + f8);
            bf16x8 v3 = *(const bf16x8*)(base + (size_t)r[3] * F + f8);
            bf16x8 v4 = *(const bf16x8*)(base + (size_t)r[4] * F + f8);
            bf16x8 v5 = *(const bf16x8*)(base + (size_t)r[5] * F + f8);
            bf16x8 v6 = *(const bf16x8*)(base + (size_t)r[6] * F + f8);
            bf16x8 v7 = *(const bf16x8*)(base + (size_t)r[7] * F + f8);
#pragma unroll
            for (int q = 0; q < 8; q++)
                acc[q] += ((d[0] * (float)v0[q] + d[1] * (float)v1[q]) + (d[2] * (float)v2[q] + d[3] * (float)v3[q])) +
                          ((d[4] * (float)v4[q] + d[5] * (float)v5[q]) + (d[6] * (float)v6[q] + d[7] * (float)v7[q]));
            e = en;
            if (!more) break;
#pragma unroll
            for (int q = 0; q < 8; q++) r[q] = rn[q];
        }
    }
    for (; e + 4 <= cnt; e += 4) {
        int r0 = list[off + e], r1 = list[off + e + 1], r2 = list[off + e + 2], r3 = list[off + e + 3];
        float d0 = dis_s[r0], d1 = dis_s[r1], d2 = dis_s[r2], d3 = dis_s[r3];
        bf16x8 v0 = *(const bf16x8*)(base + (size_t)r0 * F + f8);
        bf16x8 v1 = *(const bf16x8*)(base + (size_t)r1 * F + f8);
        bf16x8 v2 = *(const bf16x8*)(base + (size_t)r2 * F + f8);
        bf16x8 v3 = *(const bf16x8*)(base + (size_t)r3 * F + f8);
#pragma unroll
        for (int q = 0; q < 8; q++)
            acc[q] += (d0 * (float)v0[q] + d1 * (float)v1[q]) + (d2 * (float)v2[q] + d3 * (float)v3[q]);
    }
    for (; e < cnt; e++) {
        int r = list[off + e];
        float d = dis_s[r];
        bf16x8 v = *(const bf16x8*)(base + (size_t)r * F + f8);
#pragma unroll
        for (int q = 0; q < 8; q++) acc[q] += d * (float)v[q];
    }
    bf16x8 o;
#pragma unroll
    for (int q = 0; q < 8; q++) {
        float v = dj * acc[q] + bias[f8 + q];
        if (RELU) v = fmaxf(v, 0.f);
        o[q] = (bf16_t)v;
    }
    *(bf16x8*)(OUT + (size_t)j * 256 + outColOff + f8) = o;
}

// ---------------- FCN head ----------------
// register-direct split-K MFMA: 256 blocks, block b covers K chunk [b*512, b*512+512).
__global__ __launch_bounds__(256) void k_fcn1(const bf16_t* __restrict__ EMB, const float* __restrict__ W1,
                                              float* __restrict__ partials) {
    int tid = threadIdx.x, wave = tid >> 6, lane = tid & 63;
    int fm = lane & 15, fq = lane >> 4;
    int kb0 = blockIdx.x * 512;
    f32x4 acc[2][4] = {};
#pragma unroll 4
    for (int ks = 0; ks < 512; ks += 32) {
        int k = kb0 + ks + fq * 8;
        bf16x8 a0 = *(const bf16x8*)(EMB + (size_t)fm * 131072 + k);
        bf16x8 a1 = *(const bf16x8*)(EMB + (size_t)(16 + fm) * 131072 + k);
        bf16x8 bfr[4];
#pragma unroll
        for (int j = 0; j < 4; j++) {
            int n = wave * 64 + j * 16 + fm;
            const float* p = W1 + (size_t)n * 131072 + k;
            float4 lo = *(const float4*)p;
            float4 hi = *(const float4*)(p + 4);
            bf16x8 b = {(bf16_t)lo.x, (bf16_t)lo.y, (bf16_t)lo.z, (bf16_t)lo.w,
                        (bf16_t)hi.x, (bf16_t)hi.y, (bf16_t)hi.z, (bf16_t)hi.w};
            bfr[j] = b;
        }
#pragma unroll
        for (int j = 0; j < 4; j++) {
            acc[0][j] = __builtin_amdgcn_mfma_f32_16x16x32_bf16(a0, bfr[j], acc[0][j], 0, 0, 0);
            acc[1][j] = __builtin_amdgcn_mfma_f32_16x16x32_bf16(a1, bfr[j], acc[1][j], 0, 0, 0);
        }
    }
    float* P = partials + (size_t)blockIdx.x * 8192;
#pragma unroll
    for (int i = 0; i < 2; i++)
#pragma unroll
        for (int j = 0; j < 4; j++)
#pragma unroll
            for (int r = 0; r < 4; r++)
                P[(size_t)(i * 16 + fq * 4 + r) * 256 + wave * 64 + j * 16 + fm] = acc[i][j][r];
}

// reduce 256 partials -> h1pre[8192] (coalesced: thread e strides the slice dim)
__global__ __launch_bounds__(256) void k_reduce(const float* __restrict__ partials, float* __restrict__ h1pre) {
    int e = blockIdx.x * 256 + threadIdx.x;
    float s = 0;
#pragma unroll 8
    for (int i = 0; i < 256; i++) s += partials[(size_t)i * 8192 + e];
    h1pre[e] = s;
}

// final: h1 = leaky(h1pre + b1); h2 = leaky(h1@W2^T+b2); out = h2@W3^T+b3
__global__ __launch_bounds__(256) void k_head(const float* __restrict__ h1pre, const float* __restrict__ b1,
                                              const float* __restrict__ W2, const float* __restrict__ b2,
                                              const float* __restrict__ W3, const float* __restrict__ b3,
                                              float* __restrict__ out) {
    __shared__ float h1s[32][256];
    __shared__ float h2s[32][32];
    int t = threadIdx.x;
    for (int i = 0; i < 32; i++) {
        float s = h1pre[i * 256 + t] + b1[t];
        h1s[i][t] = (s > 0.f) ? s : 0.2f * s;
    }
    __syncthreads();
    for (int p = 0; p < 4; p++) {
        int id = p * 256 + t, si = id >> 5, o2 = id & 31;
        float s = 0;
        for (int k = 0; k < 256; k++) s += h1s[si][k] * W2[o2 * 256 + k];
        s += b2[o2];
        h2s[si][o2] = (s > 0.f) ? s : 0.2f * s;
    }
    __syncthreads();
    if (t < 64) {
        int si = t >> 1, o3 = t & 1;
        float s = 0;
#pragma unroll
        for (int k = 0; k < 32; k++) s += h2s[si][k] * W3[o3 * 32 + k];
        out[si * 2 + o3] = s + b3[o3];
    }
}

// ---------------- launcher ----------------

extern "C" void kernel_launch(void* const* d_in, const int* in_sizes, int n_in,
                              void* d_out, int out_size, void* d_ws, size_t ws_size,
                              hipStream_t stream) {
    const float* x = (const float*)d_in[0];
    const float* t = (const float*)d_in[1];
    const float* gum = (const float*)d_in[2];
    const int* eidx = (const int*)d_in[3];
    const float* c1w = (const float*)d_in[4];
    const float* c1b = (const float*)d_in[5];
    const float* c2w = (const float*)d_in[6];
    const float* c2b = (const float*)d_in[7];
    const float* fcw = (const float*)d_in[8];
    const float* fcb = (const float*)d_in[9];
    const float* w1 = (const float*)d_in[10];
    const float* b1 = (const float*)d_in[11];
    const float* w2 = (const float*)d_in[12];
    const float* b2 = (const float*)d_in[13];
    const float* w3 = (const float*)d_in[14];
    const float* b3 = (const float*)d_in[15];
    float* out = (float*)d_out;
    (void)in_sizes; (void)n_in; (void)out_size; (void)ws_size;

    char* ws = (char*)d_ws;
    size_t off = 0;
    auto alloc = [&](size_t bytes) -> char* {
        char* p = ws + off;
        off += (bytes + 255) & ~size_t(255);
        return p;
    };
    bf16_t* c1wb = (bf16_t*)alloc((size_t)256 * 512 * 2);
    bf16_t* c2wb = (bf16_t*)alloc((size_t)128 * 256 * 2);
    float4* lsr = (float4*)alloc((size_t)kNTOT * 16);
    bf16_t* AT = (bf16_t*)alloc((size_t)kBZ * kN * kN * 2);          // 16.8 MB
    float* degsum = (float*)alloc((size_t)kNTOT * 4);
    bf16_t* XW1_EMB = (bf16_t*)alloc((size_t)kNTOT * 256 * 2);       // 8.4 MB (XW1 then EMB)
    bf16_t* Z1T = (bf16_t*)alloc((size_t)kBZ * 256 * 512 * 2);       // 8.4 MB
    bf16_t* H = (bf16_t*)alloc((size_t)32768 * 256 * 2);             // 16.8 MB
    bf16_t* XW2 = (bf16_t*)alloc((size_t)32768 * 128 * 2);           // 8.4 MB
    bf16_t* Z2T = (bf16_t*)alloc((size_t)kBZ * 128 * 512 * 2);       // 4.2 MB
    int* counts = (int*)alloc((size_t)kNTOT * 4);
    int* offsets = (int*)alloc((size_t)kNTOT * 4);
    int* cursor = (int*)alloc((size_t)kNTOT * 4);
    float* diss = (float*)alloc((size_t)kNTOT * 4);
    int* list = (int*)alloc((size_t)kE * 4);
    float* partials = (float*)alloc((size_t)256 * 8192 * 4);         // 8.4 MB
    float* h1pre = (float*)alloc((size_t)8192 * 4);

    bf16_t* XW1 = XW1_EMB;
    bf16_t* EMB = XW1_EMB;  // EMB written only after XW1's last read (sparse L1)

    // front: weight cvt + zero counts/degsum + lsr
    k_front<<<4288, 256, 0, stream>>>(c1w, c2w, c1wb, c2wb, counts, degsum, t, fcw, fcb, lsr);
    k_adj<<<dim3(8, 8, 32), 256, 0, stream>>>(gum, lsr, AT, degsum);
    // sparse CSR build
    k_hist<<<2048, 256, 0, stream>>>(eidx + kE, counts);
    k_scan<<<1, 1024, 0, stream>>>(counts, offsets, cursor, diss);
    k_fill<<<2048, 256, 0, stream>>>(eidx, eidx + kE, cursor, list);
    // XW1 = x @ conv1_w^T (fp32 A reg-staged) + Z1T scaled transpose
    k_gemmT<true, 256, kNTOT><<<dim3(128, 2, 1), 256, 0, stream>>>(x, c1wb, XW1, Z1T, 512, degsum);
    // dense layer 1: H[dense] = relu(dis*(AT@Z1) + b1)
    k_gemm<1><<<dim3(4, 2, 32), 256, 0, stream>>>(AT, Z1T, H, 512, 512, 512, 256,
                                                  (size_t)512 * 512, (size_t)256 * 512, (size_t)512 * 256,
                                                  degsum, c1b);
    // sparse layer 1 -> H rows 16384..
    k_sagg<256, true><<<2048, 256, 0, stream>>>(XW1, 0, list, offsets, counts, diss, c1b,
                                                H + (size_t)16384 * 256, 0);
    // stacked layer-2 matmul: XW2 = H @ conv2_w^T (+ Z2T for dense rows)
    k_gemmT<false, 128, kNTOT><<<dim3(256, 1, 1), 256, 0, stream>>>(H, c2wb, XW2, Z2T, 256, degsum);
    // dense layer 2 -> EMB cols 0..127
    k_gemm<2><<<dim3(4, 1, 32), 256, 0, stream>>>(AT, Z2T, EMB, 512, 512, 512, 256,
                                                  (size_t)512 * 512, (size_t)128 * 512, (size_t)512 * 256,
                                                  degsum, c2b);
    // sparse layer 2 -> EMB cols 128..255
    k_sagg<128, false><<<1024, 256, 0, stream>>>(XW2, 16384, list, offsets, counts, diss, c2b, EMB, 128);
    // FCN head
    k_fcn1<<<256, 256, 0, stream>>>(EMB, w1, partials);
    k_reduce<<<32, 256, 0, stream>>>(partials, h1pre);
    k_head<<<1, 256, 0, stream>>>(h1pre, b1, w2, b2, w3, b3, out);
}

// Round 3
// 484.742 us; speedup vs baseline: 1.0670x; 1.0441x over previous
//
#include <hip/hip_runtime.h>
#include <hip/hip_bf16.h>

typedef __bf16 bf16_t;
typedef __bf16 bf16x8 __attribute__((ext_vector_type(8)));
typedef __bf16 bf16x4 __attribute__((ext_vector_type(4)));
typedef float f32x4 __attribute__((ext_vector_type(4)));

constexpr int kN = 512;       // nodes per sample
constexpr int kBZ = 32;       // batch
constexpr int kTC = 256;
constexpr int kE = 524288;
constexpr int kNTOT = 16384;  // kBZ*kN

// ---- async global->LDS helpers (16B, XOR chunk swizzle, rule #21 both-sides) ----
__device__ __forceinline__ void gll16(const bf16_t* g, bf16_t* l) {
    __builtin_amdgcn_global_load_lds((const __attribute__((address_space(1))) void*)g,
                                     (__attribute__((address_space(3))) void*)l, 16, 0, 0);
}

// stage a 128x64 bf16 tile (row-major src, row stride ld elems) into linear LDS [128][64].
// 16B chunk c of row r stored at slot (c ^ (r&7)). 4 global_load_lds per wave (8 rows each).
__device__ __forceinline__ void stage128x64(const bf16_t* __restrict__ src, int ld,
                                            bf16_t* lds, int wave, int lane) {
#pragma unroll
    for (int i = 0; i < 4; i++) {
        int r0 = (wave * 4 + i) * 8;
        int r = r0 + (lane >> 3);
        int c = (lane & 7) ^ (r & 7);
        gll16(src + (size_t)r * ld + c * 8, lds + r0 * 64);
    }
}

// read 16B fragment (8 bf16) at (row, 16B-chunk cc) from swizzled [128][64] tile
__device__ __forceinline__ bf16x8 rdfrag(const bf16_t* lds, int row, int cc) {
    return *(const bf16x8*)(lds + row * 64 + ((cc ^ (row & 7)) * 8));
}

// ---------------- front: weight convert + zero-init + lsr ----------------
__global__ __launch_bounds__(256) void k_front(const float* __restrict__ c1w, const float* __restrict__ c2w,
                                               bf16_t* __restrict__ c1b, bf16_t* __restrict__ c2b,
                                               int* __restrict__ counts, float* __restrict__ degsum,
                                               const float* __restrict__ tin, const float* __restrict__ fcw,
                                               const float* __restrict__ fcb, float4* __restrict__ lsr) {
    int b = blockIdx.x;
    if (b < 192) {
        int i = b * 256 + threadIdx.x;
        const int n0 = 32768, n1 = n0 + 8192, n2 = n1 + 4096, n3 = n2 + 4096;
        if (i < n0) {
            float4 v = ((const float4*)c1w)[i];
            bf16x4 o = {(bf16_t)v.x, (bf16_t)v.y, (bf16_t)v.z, (bf16_t)v.w};
            ((bf16x4*)c1b)[i] = o;
        } else if (i < n1) {
            int j = i - n0;
            float4 v = ((const float4*)c2w)[j];
            bf16x4 o = {(bf16_t)v.x, (bf16_t)v.y, (bf16_t)v.z, (bf16_t)v.w};
            ((bf16x4*)c2b)[j] = o;
        } else if (i < n2) {
            ((int4*)counts)[i - n1] = make_int4(0, 0, 0, 0);
        } else if (i < n3) {
            ((float4*)degsum)[i - n2] = make_float4(0.f, 0.f, 0.f, 0.f);
        }
    } else {
        int row = (b - 192) * 4 + (threadIdx.x >> 6);
        int lane = threadIdx.x & 63;
        const float* tr = tin + (size_t)row * kTC;
        float s0 = 0, s1 = 0, r0 = 0, r1 = 0;
        for (int k = lane; k < kTC; k += 64) {
            float u = fmaxf(tr[k], 0.f);
            s0 += u * fcw[k];
            s1 += u * fcw[512 + k];
            r0 += u * fcw[256 + k];
            r1 += u * fcw[768 + k];
        }
#pragma unroll
        for (int off = 32; off > 0; off >>= 1) {
            s0 += __shfl_down(s0, off); s1 += __shfl_down(s1, off);
            r0 += __shfl_down(r0, off); r1 += __shfl_down(r1, off);
        }
        if (lane == 0) lsr[row] = make_float4(s0 + fcb[0], s1 + fcb[1], r0, r1);
    }
}

// merged: blocks [0,2048) = adj tiles; blocks [2048,4096) = hist chunks (independent work).
// Ah_T[s][j][i] = (argmax==0) + (i==j); accumulates degsum[j] via atomics.
__global__ __launch_bounds__(256) void k_adjhist(const float* __restrict__ gum, const float4* __restrict__ lsr,
                                                 bf16_t* __restrict__ AT, float* __restrict__ degsum,
                                                 const int* __restrict__ col, int* __restrict__ counts) {
    int blk = blockIdx.x;
    if (blk >= 2048) {
        int e = (blk - 2048) * 256 + threadIdx.x;
        if (e < kE) atomicAdd(&counts[col[e]], 1);
        return;
    }
    int s = blk >> 6;
    int a0 = ((blk >> 3) & 7) * 64, b0 = (blk & 7) * 64;
    __shared__ bf16_t tile[64][72];
    int t = threadIdx.x;
    int lb = t & 63, ra = t >> 6;
    int b = b0 + lb;
    float4 pb = lsr[s * kN + b];
#pragma unroll 4
    for (int p = 0; p < 16; p++) {
        int a = a0 + p * 4 + ra;
        float4 qa = lsr[s * kN + a];
        float2 gv = *(const float2*)(gum + ((((size_t)s * kN + a) * kN + b) << 1));
        float u0 = fmaxf(gv.x, 1e-9f);
        float u1 = fmaxf(gv.y, 1e-9f);
        float g0 = -__logf(-__logf(u0));
        float g1 = -__logf(-__logf(u1));
        float v = ((qa.z + pb.x + g0) >= (qa.w + pb.y + g1)) ? 1.f : 0.f;
        if (a == b) v += 1.f;
        tile[lb][p * 4 + ra] = (bf16_t)v;
    }
    __syncthreads();
    int rj = t >> 3, li = (t & 7) * 8;
#pragma unroll
    for (int p = 0; p < 2; p++) {
        int j = p * 32 + rj;
        bf16x8 v = *(const bf16x8*)&tile[j][li];
        *(bf16x8*)(AT + ((size_t)s * kN + b0 + j) * kN + a0 + li) = v;
        float ps = 0;
#pragma unroll
        for (int q = 0; q < 8; q++) ps += (float)v[q];
        ps += __shfl_down(ps, 4);
        ps += __shfl_down(ps, 2);
        ps += __shfl_down(ps, 1);
        if ((t & 7) == 0) atomicAdd(degsum + s * kN + b0 + j, ps);
    }
}

// ---------------- bf16 NT GEMM: C(MxN) = A(MxK) * B(NxK)^T, 128x128 tile, BK=64 ----------------
// GDEC=1: flat 256 blocks, XCD-paired so the 2 y-blocks sharing an A-tile land on one XCD L2.
// GDEC=2: flat 128 blocks, XCD-paired so the 4 x-blocks sharing the B panel land on one XCD L2.
// MODE 1: C = relu(rsqrt(deg[row])*acc + bias[col]). MODE 2: same, no relu.
template <int MODE, int GDEC>
__global__ __launch_bounds__(256) void k_gemm(const bf16_t* __restrict__ A, const bf16_t* __restrict__ B,
                                              bf16_t* __restrict__ C, int K, int lda, int ldb, int ldc,
                                              size_t sA, size_t sB, size_t sC,
                                              const float* __restrict__ degsum, const float* __restrict__ bias) {
    int m0, n0, s;
    {
        int f = blockIdx.x;
        if constexpr (GDEC == 1) {
            int p = ((f >> 4) << 3) | (f & 7);  // [0,128)
            int y = (f >> 3) & 1;
            s = p >> 2;
            m0 = (p & 3) * 128;
            n0 = y * 128;
        } else {
            s = ((f >> 5) << 3) | (f & 7);      // [0,32)
            m0 = ((f >> 3) & 3) * 128;
            n0 = 0;
        }
    }
    const bf16_t* Ab = A + sA * s + (size_t)m0 * lda;
    const bf16_t* Bb = B + sB * s + (size_t)n0 * ldb;
    C += sC * s;
    __shared__ __align__(16) bf16_t As[2][128 * 64], Bs[2][128 * 64];
    f32x4 acc[4][4] = {};
    int tid = threadIdx.x;
    int wave = tid >> 6, lane = tid & 63;
    int wm = (wave & 1) * 64, wn = (wave >> 1) * 64;
    int fm = lane & 15, fq = lane >> 4;
    stage128x64(Ab, lda, As[0], wave, lane);
    stage128x64(Bb, ldb, Bs[0], wave, lane);
    int cur = 0;
    for (int kb = 0;;) {
        int kn = kb + 64;
        __syncthreads();  // drains vmcnt: buf[cur] staged; buf[cur^1] reads (prev iter) done
        if (kn < K) {
            stage128x64(Ab + kn, lda, As[cur ^ 1], wave, lane);
            stage128x64(Bb + kn, ldb, Bs[cur ^ 1], wave, lane);
        }
#pragma unroll
        for (int kk = 0; kk < 2; kk++) {
            bf16x8 af[4], bfr[4];
#pragma unroll
            for (int i = 0; i < 4; i++) {
                af[i] = rdfrag(As[cur], wm + i * 16 + fm, kk * 4 + fq);
                bfr[i] = rdfrag(Bs[cur], wn + i * 16 + fm, kk * 4 + fq);
            }
#pragma unroll
            for (int i = 0; i < 4; i++)
#pragma unroll
                for (int j = 0; j < 4; j++)
                    acc[i][j] = __builtin_amdgcn_mfma_f32_16x16x32_bf16(af[i], bfr[j], acc[i][j], 0, 0, 0);
        }
        kb = kn;
        if (kb >= K) break;
        cur ^= 1;
    }
#pragma unroll
    for (int i = 0; i < 4; i++) {
#pragma unroll
        for (int r = 0; r < 4; r++) {
            int row = wm + i * 16 + fq * 4 + r;
            float sc = rsqrtf(degsum[(size_t)s * kN + m0 + row]);
#pragma unroll
            for (int j = 0; j < 4; j++) {
                int col = n0 + wn + j * 16 + fm;
                float v = sc * acc[i][j][r] + bias[col];
                if constexpr (MODE == 1) v = fmaxf(v, 0.f);
                C[(size_t)(m0 + row) * ldc + col] = (bf16_t)v;
            }
        }
    }
}

// ---- fused GEMM variants producing XW (plain) + ZT (scaled transpose) ----
// AF32: A operand is fp32, reg-staged (issue-early / write-late). F = output cols.
// PAIRXY: flat 256-block grid, XCD-paired so the 2 y-blocks sharing an A-tile co-reside.
// ZT[s][f][i] = rsqrt(deg[row]) * XW[row][f], row = s*512+i. DENSE_ROWS limits ZT writes.
template <bool AF32, int F, int DENSE_ROWS, bool PAIRXY>
__global__ __launch_bounds__(256) void k_gemmT(const void* __restrict__ Ap, const bf16_t* __restrict__ B,
                                               bf16_t* __restrict__ XW, bf16_t* __restrict__ ZT, int K,
                                               const float* __restrict__ degsum) {
    int m0, n0;
    if constexpr (PAIRXY) {
        int f = blockIdx.x;
        m0 = (((f >> 4) << 3) | (f & 7)) * 128;  // [0,128) pair index
        n0 = ((f >> 3) & 1) * 128;
    } else {
        m0 = blockIdx.x * 128;
        n0 = blockIdx.y * 128;
    }
    constexpr int AST = AF32 ? 9216 : 8192;  // per-buffer A elems (padded [128][72] when fp32-staged)
    __shared__ __align__(16) bf16_t smem[2 * AST + 2 * 8192];
    bf16_t* A0 = smem;
    bf16_t* A1 = smem + AST;
    bf16_t* B0 = smem + 2 * AST;
    bf16_t* B1 = smem + 2 * AST + 8192;
    f32x4 acc[4][4] = {};
    int tid = threadIdx.x;
    int wave = tid >> 6, lane = tid & 63;
    int wm = (wave & 1) * 64, wn = (wave >> 1) * 64;
    int fm = lane & 15, fq = lane >> 4;
    int srow = tid >> 3, scol = (tid & 7) * 8;
    const float* Af = (const float*)Ap;
    const bf16_t* Abf = (const bf16_t*)Ap;
    // prologue: stage tile 0
    if constexpr (AF32) {
#pragma unroll
        for (int p = 0; p < 4; p++) {
            int row = p * 32 + srow;
            const float* ap = Af + (size_t)(m0 + row) * K + scol;
            float4 lo = *(const float4*)ap, hi = *(const float4*)(ap + 4);
            bf16x8 o = {(bf16_t)lo.x, (bf16_t)lo.y, (bf16_t)lo.z, (bf16_t)lo.w,
                        (bf16_t)hi.x, (bf16_t)hi.y, (bf16_t)hi.z, (bf16_t)hi.w};
            *(bf16x8*)&A0[row * 72 + scol] = o;
        }
    } else {
        stage128x64(Abf + (size_t)m0 * K, K, A0, wave, lane);
    }
    stage128x64(B + (size_t)n0 * K, K, B0, wave, lane);
    int cur = 0;
    for (int kb = 0;;) {
        int kn = kb + 64;
        bool more = kn < K;
        bf16_t* Ac = cur ? A1 : A0;
        bf16_t* An = cur ? A0 : A1;
        bf16_t* Bc = cur ? B1 : B0;
        bf16_t* Bn = cur ? B0 : B1;
        float4 plo[4], phi[4];
        __syncthreads();
        if (more) {
            if constexpr (AF32) {
#pragma unroll
                for (int p = 0; p < 4; p++) {  // issue-early: loads fly during MFMA below
                    int row = p * 32 + srow;
                    const float* ap = Af + (size_t)(m0 + row) * K + kn + scol;
                    plo[p] = *(const float4*)ap;
                    phi[p] = *(const float4*)(ap + 4);
                }
            } else {
                stage128x64(Abf + (size_t)m0 * K + kn, K, An, wave, lane);
            }
            stage128x64(B + (size_t)n0 * K + kn, K, Bn, wave, lane);
        }
#pragma unroll
        for (int kk = 0; kk < 2; kk++) {
            bf16x8 af[4], bfr[4];
#pragma unroll
            for (int i = 0; i < 4; i++) {
                if constexpr (AF32)
                    af[i] = *(const bf16x8*)&Ac[(wm + i * 16 + fm) * 72 + kk * 32 + fq * 8];
                else
                    af[i] = rdfrag(Ac, wm + i * 16 + fm, kk * 4 + fq);
                bfr[i] = rdfrag(Bc, wn + i * 16 + fm, kk * 4 + fq);
            }
#pragma unroll
            for (int i = 0; i < 4; i++)
#pragma unroll
                for (int j = 0; j < 4; j++)
                    acc[i][j] = __builtin_amdgcn_mfma_f32_16x16x32_bf16(af[i], bfr[j], acc[i][j], 0, 0, 0);
        }
        if constexpr (AF32) {
            if (more) {  // write-late: cvt + ds_write after compute
#pragma unroll
                for (int p = 0; p < 4; p++) {
                    int row = p * 32 + srow;
                    bf16x8 o = {(bf16_t)plo[p].x, (bf16_t)plo[p].y, (bf16_t)plo[p].z, (bf16_t)plo[p].w,
                                (bf16_t)phi[p].x, (bf16_t)phi[p].y, (bf16_t)phi[p].z, (bf16_t)phi[p].w};
                    *(bf16x8*)&An[row * 72 + scol] = o;
                }
            }
        }
        kb = kn;
        if (kb >= K) break;
        cur ^= 1;
    }
    // write XW (unscaled) + stage scaled values into LDS transposed
    bool doT = (m0 < DENSE_ROWS);
    __syncthreads();  // all LDS ops of the K-loop complete before reuse as T[128][136]
#pragma unroll
    for (int i = 0; i < 4; i++) {
#pragma unroll
        for (int r = 0; r < 4; r++) {
            int row = wm + i * 16 + fq * 4 + r;
            float sc = doT ? rsqrtf(degsum[m0 + row]) : 0.f;
#pragma unroll
            for (int j = 0; j < 4; j++) {
                int col = wn + j * 16 + fm;
                float v = acc[i][j][r];
                XW[(size_t)(m0 + row) * F + n0 + col] = (bf16_t)v;
                if (doT) smem[col * 136 + row] = (bf16_t)(sc * v);
            }
        }
    }
    if (doT) {
        __syncthreads();
        int fr = tid >> 1, hi = (tid & 1) * 64;
        bf16_t* zrow = ZT + ((size_t)(m0 >> 9) * F + n0 + fr) * kN + (m0 & 511) + hi;
#pragma unroll
        for (int q = 0; q < 8; q++)
            *(bf16x8*)(zrow + q * 8) = *(const bf16x8*)&smem[fr * 136 + hi + q * 8];
    }
}

// ---------------- sparse path ----------------

// single block, 1024 threads; padded LDS indexing (j + j/32) to avoid bank conflicts
__global__ __launch_bounds__(1024) void k_scan(const int* __restrict__ counts, int* __restrict__ offsets,
                                               int* __restrict__ cursor, float* __restrict__ dis_s) {
    __shared__ int ldc_[16896];
    __shared__ int sums[1024];
    int t = threadIdx.x;
#define IDX(j) ((j) + ((j) >> 5))
    for (int i = 0; i < 16; i++) {
        int g = i * 1024 + t;
        int c = counts[g];
        ldc_[IDX(g)] = c;
        dis_s[g] = rsqrtf((float)(c + 1));  // deg includes self loop
    }
    __syncthreads();
    int s = 0;
    for (int i = 0; i < 16; i++) s += ldc_[IDX(t * 16 + i)];
    sums[t] = s;
    __syncthreads();
    for (int off = 1; off < 1024; off <<= 1) {
        int y = (t >= off) ? sums[t - off] : 0;
        __syncthreads();
        sums[t] += y;
        __syncthreads();
    }
    int run = sums[t] - s;  // exclusive prefix
    for (int i = 0; i < 16; i++) {
        int j = t * 16 + i;
        int c = ldc_[IDX(j)];
        ldc_[IDX(j)] = run;
        run += c;
    }
    __syncthreads();
    for (int i = 0; i < 16; i++) {
        int g = i * 1024 + t;
        int o = ldc_[IDX(g)];
        offsets[g] = o;
        cursor[g] = o;
    }
#undef IDX
}

__global__ __launch_bounds__(256) void k_fill(const int* __restrict__ row, const int* __restrict__ col,
                                              int* __restrict__ cursor, int* __restrict__ list) {
    int e = blockIdx.x * 256 + threadIdx.x;
    if (e < kE) {
        int p = atomicAdd(&cursor[col[e]], 1);
        list[p] = row[e];
    }
}

// out[j,f8..f8+7] via bf16x8 gathers; OUT row j, ld 256. List-prefetch software pipeline.
template <int F, bool RELU>
__global__ __launch_bounds__(256) void k_sagg(const bf16_t* __restrict__ XW, int rowOffIn,
                                              const int* __restrict__ list, const int* __restrict__ offsets,
                                              const int* __restrict__ counts, const float* __restrict__ dis_s,
                                              const float* __restrict__ bias, bf16_t* __restrict__ OUT,
                                              int outColOff) {
    constexpr int TPR = F / 8;        // threads per row
    constexpr int RPB = 256 / TPR;    // rows per block
    int j = blockIdx.x * RPB + threadIdx.x / TPR;
    int f8 = (threadIdx.x % TPR) * 8;
    float dj = dis_s[j];
    const bf16_t* base = XW + (size_t)rowOffIn * F;
    float acc[8];
    {
        bf16x8 v = *(const bf16x8*)(base + (size_t)j * F + f8);
#pragma unroll
        for (int q = 0; q < 8; q++) acc[q] = dj * (float)v[q];
    }
    int off = offsets[j], cnt = counts[j];
    int e = 0;
    int nb = cnt & ~7;
    if (nb) {
        int r[8];
#pragma unroll
        for (int q = 0; q < 8; q++) r[q] = list[off + q];
        while (true) {
            int en = e + 8;
            bool more = en < nb;
            int rn[8];
            if (more) {
#pragma unroll
                for (int q = 0; q < 8; q++) rn[q] = list[off + en + q];
            }
            float d[8];
#pragma unroll
            for (int q = 0; q < 8; q++) d[q] = dis_s[r[q]];
            bf16x8 v0 = *(const bf16x8*)(base + (size_t)r[0] * F + f8);
            bf16x8 v1 = *(const bf16x8*)(base + (size_t)r[1] * F + f8);
            bf16x8 v2 = *(const bf16x8*)(base + (size_t)r[2] * F + f8);
            bf16x8 v3 = *(const bf16x8*)(base + (size_t)r[3] * F + f8);
            bf16x8 v4 = *(const bf16x8*)(base + (size_t)r[4] * F + f8);
            bf16x8 v5 = *(const bf16x8*)(base + (size_t)r[5] * F + f8);
            bf16x8 v6 = *(const bf16x8*)(base + (size_t)r[6] * F + f8);
            bf16x8 v7 = *(const bf16x8*)(base + (size_t)r[7] * F + f8);
#pragma unroll
            for (int q = 0; q < 8; q++)
                acc[q] += ((d[0] * (float)v0[q] + d[1] * (float)v1[q]) + (d[2] * (float)v2[q] + d[3] * (float)v3[q])) +
                          ((d[4] * (float)v4[q] + d[5] * (float)v5[q]) + (d[6] * (float)v6[q] + d[7] * (float)v7[q]));
            e = en;
            if (!more) break;
#pragma unroll
            for (int q = 0; q < 8; q++) r[q] = rn[q];
        }
    }
    for (; e + 4 <= cnt; e += 4) {
        int r0 = list[off + e], r1 = list[off + e + 1], r2 = list[off + e + 2], r3 = list[off + e + 3];
        float d0 = dis_s[r0], d1 = dis_s[r1], d2 = dis_s[r2], d3 = dis_s[r3];
        bf16x8 v0 = *(const bf16x8*)(base + (size_t)r0 * F + f8);
        bf16x8 v1 = *(const bf16x8*)(base + (size_t)r1 * F + f8);
        bf16x8 v2 = *(const bf16x8*)(base + (size_t)r2 * F + f8);
        bf16x8 v3 = *(const bf16x8*)(base + (size_t)r3 * F + f8);
#pragma unroll
        for (int q = 0; q < 8; q++)
            acc[q] += (d0 * (float)v0[q] + d1 * (float)v1[q]) + (d2 * (float)v2[q] + d3 * (float)v3[q]);
    }
    for (; e < cnt; e++) {
        int r = list[off + e];
        float d = dis_s[r];
        bf16x8 v = *(const bf16x8*)(base + (size_t)r * F + f8);
#pragma unroll
        for (int q = 0; q < 8; q++) acc[q] += d * (float)v[q];
    }
    bf16x8 o;
#pragma unroll
    for (int q = 0; q < 8; q++) {
        float v = dj * acc[q] + bias[f8 + q];
        if (RELU) v = fmaxf(v, 0.f);
        o[q] = (bf16_t)v;
    }
    *(bf16x8*)(OUT + (size_t)j * 256 + outColOff + f8) = o;
}

// ---------------- FCN head ----------------
// register-direct split-K MFMA: 256 blocks, block b covers K chunk [b*512, b*512+512).
__global__ __launch_bounds__(256) void k_fcn1(const bf16_t* __restrict__ EMB, const float* __restrict__ W1,
                                              float* __restrict__ partials) {
    int tid = threadIdx.x, wave = tid >> 6, lane = tid & 63;
    int fm = lane & 15, fq = lane >> 4;
    int kb0 = blockIdx.x * 512;
    f32x4 acc[2][4] = {};
#pragma unroll 4
    for (int ks = 0; ks < 512; ks += 32) {
        int k = kb0 + ks + fq * 8;
        bf16x8 a0 = *(const bf16x8*)(EMB + (size_t)fm * 131072 + k);
        bf16x8 a1 = *(const bf16x8*)(EMB + (size_t)(16 + fm) * 131072 + k);
        bf16x8 bfr[4];
#pragma unroll
        for (int j = 0; j < 4; j++) {
            int n = wave * 64 + j * 16 + fm;
            const float* p = W1 + (size_t)n * 131072 + k;
            float4 lo = *(const float4*)p;
            float4 hi = *(const float4*)(p + 4);
            bf16x8 b = {(bf16_t)lo.x, (bf16_t)lo.y, (bf16_t)lo.z, (bf16_t)lo.w,
                        (bf16_t)hi.x, (bf16_t)hi.y, (bf16_t)hi.z, (bf16_t)hi.w};
            bfr[j] = b;
        }
#pragma unroll
        for (int j = 0; j < 4; j++) {
            acc[0][j] = __builtin_amdgcn_mfma_f32_16x16x32_bf16(a0, bfr[j], acc[0][j], 0, 0, 0);
            acc[1][j] = __builtin_amdgcn_mfma_f32_16x16x32_bf16(a1, bfr[j], acc[1][j], 0, 0, 0);
        }
    }
    float* P = partials + (size_t)blockIdx.x * 8192;
#pragma unroll
    for (int i = 0; i < 2; i++)
#pragma unroll
        for (int j = 0; j < 4; j++)
#pragma unroll
            for (int r = 0; r < 4; r++)
                P[(size_t)(i * 16 + fq * 4 + r) * 256 + wave * 64 + j * 16 + fm] = acc[i][j][r];
}

// reduce 256 partials -> h1pre[8192]. 256 blocks: block b covers 32 outputs, 8-way slice split.
__global__ __launch_bounds__(256) void k_reduce(const float* __restrict__ partials, float* __restrict__ h1pre) {
    __shared__ float red[8][32];
    int t = threadIdx.x;
    int el = t & 31, q = t >> 5;
    int e = blockIdx.x * 32 + el;
    float s = 0;
#pragma unroll 8
    for (int i = 0; i < 32; i++) s += partials[(size_t)(q * 32 + i) * 8192 + e];
    red[q][el] = s;
    __syncthreads();
    if (t < 32) {
        float r = 0;
#pragma unroll
        for (int qq = 0; qq < 8; qq++) r += red[qq][t];
        h1pre[blockIdx.x * 32 + t] = r;
    }
}

// final: h1 = leaky(h1pre + b1); h2 = leaky(h1@W2^T+b2); out = h2@W3^T+b3
__global__ __launch_bounds__(256) void k_head(const float* __restrict__ h1pre, const float* __restrict__ b1,
                                              const float* __restrict__ W2, const float* __restrict__ b2,
                                              const float* __restrict__ W3, const float* __restrict__ b3,
                                              float* __restrict__ out) {
    __shared__ float h1s[32][256];
    __shared__ float h2s[32][32];
    int t = threadIdx.x;
    for (int i = 0; i < 32; i++) {
        float s = h1pre[i * 256 + t] + b1[t];
        h1s[i][t] = (s > 0.f) ? s : 0.2f * s;
    }
    __syncthreads();
    for (int p = 0; p < 4; p++) {
        int id = p * 256 + t, si = id >> 5, o2 = id & 31;
        float s = 0;
        for (int k = 0; k < 256; k++) s += h1s[si][k] * W2[o2 * 256 + k];
        s += b2[o2];
        h2s[si][o2] = (s > 0.f) ? s : 0.2f * s;
    }
    __syncthreads();
    if (t < 64) {
        int si = t >> 1, o3 = t & 1;
        float s = 0;
#pragma unroll
        for (int k = 0; k < 32; k++) s += h2s[si][k] * W3[o3 * 32 + k];
        out[si * 2 + o3] = s + b3[o3];
    }
}

// ---------------- launcher ----------------

extern "C" void kernel_launch(void* const* d_in, const int* in_sizes, int n_in,
                              void* d_out, int out_size, void* d_ws, size_t ws_size,
                              hipStream_t stream) {
    const float* x = (const float*)d_in[0];
    const float* t = (const float*)d_in[1];
    const float* gum = (const float*)d_in[2];
    const int* eidx = (const int*)d_in[3];
    const float* c1w = (const float*)d_in[4];
    const float* c1b = (const float*)d_in[5];
    const float* c2w = (const float*)d_in[6];
    const float* c2b = (const float*)d_in[7];
    const float* fcw = (const float*)d_in[8];
    const float* fcb = (const float*)d_in[9];
    const float* w1 = (const float*)d_in[10];
    const float* b1 = (const float*)d_in[11];
    const float* w2 = (const float*)d_in[12];
    const float* b2 = (const float*)d_in[13];
    const float* w3 = (const float*)d_in[14];
    const float* b3 = (const float*)d_in[15];
    float* out = (float*)d_out;
    (void)in_sizes; (void)n_in; (void)out_size; (void)ws_size;

    char* ws = (char*)d_ws;
    size_t off = 0;
    auto alloc = [&](size_t bytes) -> char* {
        char* p = ws + off;
        off += (bytes + 255) & ~size_t(255);
        return p;
    };
    bf16_t* c1wb = (bf16_t*)alloc((size_t)256 * 512 * 2);
    bf16_t* c2wb = (bf16_t*)alloc((size_t)128 * 256 * 2);
    float4* lsr = (float4*)alloc((size_t)kNTOT * 16);
    bf16_t* AT = (bf16_t*)alloc((size_t)kBZ * kN * kN * 2);          // 16.8 MB
    float* degsum = (float*)alloc((size_t)kNTOT * 4);
    bf16_t* XW1_EMB = (bf16_t*)alloc((size_t)kNTOT * 256 * 2);       // 8.4 MB (XW1 then EMB)
    bf16_t* Z1T = (bf16_t*)alloc((size_t)kBZ * 256 * 512 * 2);       // 8.4 MB
    bf16_t* H = (bf16_t*)alloc((size_t)32768 * 256 * 2);             // 16.8 MB
    bf16_t* XW2 = (bf16_t*)alloc((size_t)32768 * 128 * 2);           // 8.4 MB
    bf16_t* Z2T = (bf16_t*)alloc((size_t)kBZ * 128 * 512 * 2);       // 4.2 MB
    int* counts = (int*)alloc((size_t)kNTOT * 4);
    int* offsets = (int*)alloc((size_t)kNTOT * 4);
    int* cursor = (int*)alloc((size_t)kNTOT * 4);
    float* diss = (float*)alloc((size_t)kNTOT * 4);
    int* list = (int*)alloc((size_t)kE * 4);
    float* partials = (float*)alloc((size_t)256 * 8192 * 4);         // 8.4 MB
    float* h1pre = (float*)alloc((size_t)8192 * 4);

    bf16_t* XW1 = XW1_EMB;
    bf16_t* EMB = XW1_EMB;  // EMB written only after XW1's last read (sparse L1)

    // front: weight cvt + zero counts/degsum + lsr
    k_front<<<4288, 256, 0, stream>>>(c1w, c2w, c1wb, c2wb, counts, degsum, t, fcw, fcb, lsr);
    // adj tiles + edge histogram (independent work, one dispatch)
    k_adjhist<<<4096, 256, 0, stream>>>(gum, lsr, AT, degsum, eidx + kE, counts);
    k_scan<<<1, 1024, 0, stream>>>(counts, offsets, cursor, diss);
    k_fill<<<2048, 256, 0, stream>>>(eidx, eidx + kE, cursor, list);
    // XW1 = x @ conv1_w^T (fp32 A reg-staged) + Z1T scaled transpose; XCD-paired grid
    k_gemmT<true, 256, kNTOT, true><<<256, 256, 0, stream>>>(x, c1wb, XW1, Z1T, 512, degsum);
    // dense layer 1: H[dense] = relu(dis*(AT@Z1) + b1); XCD-paired grid
    k_gemm<1, 1><<<256, 256, 0, stream>>>(AT, Z1T, H, 512, 512, 512, 256,
                                          (size_t)512 * 512, (size_t)256 * 512, (size_t)512 * 256,
                                          degsum, c1b);
    // sparse layer 1 -> H rows 16384..
    k_sagg<256, true><<<2048, 256, 0, stream>>>(XW1, 0, list, offsets, counts, diss, c1b,
                                                H + (size_t)16384 * 256, 0);
    // stacked layer-2 matmul: XW2 = H @ conv2_w^T (+ Z2T for dense rows)
    k_gemmT<false, 128, kNTOT, false><<<dim3(256, 1, 1), 256, 0, stream>>>(H, c2wb, XW2, Z2T, 256, degsum);
    // dense layer 2 -> EMB cols 0..127; XCD-paired grid
    k_gemm<2, 2><<<128, 256, 0, stream>>>(AT, Z2T, EMB, 512, 512, 512, 256,
                                          (size_t)512 * 512, (size_t)128 * 512, (size_t)512 * 256,
                                          degsum, c2b);
    // sparse layer 2 -> EMB cols 128..255
    k_sagg<128, false><<<1024, 256, 0, stream>>>(XW2, 16384, list, offsets, counts, diss, c2b, EMB, 128);
    // FCN head
    k_fcn1<<<256, 256, 0, stream>>>(EMB, w1, partials);
    k_reduce<<<256, 256, 0, stream>>>(partials, h1pre);
    k_head<<<1, 256, 0, stream>>>(h1pre, b1, w2, b2, w3, b3, out);
}

// Round 4
// 482.422 us; speedup vs baseline: 1.0722x; 1.0048x over previous
//
#include <hip/hip_runtime.h>
#include <hip/hip_bf16.h>

typedef __bf16 bf16_t;
typedef __bf16 bf16x8 __attribute__((ext_vector_type(8)));
typedef __bf16 bf16x4 __attribute__((ext_vector_type(4)));
typedef float f32x4 __attribute__((ext_vector_type(4)));

constexpr int kN = 512;       // nodes per sample
constexpr int kBZ = 32;       // batch
constexpr int kTC = 256;
constexpr int kE = 524288;
constexpr int kNTOT = 16384;  // kBZ*kN

// ---- async global->LDS helpers (16B, XOR chunk swizzle, rule #21 both-sides) ----
__device__ __forceinline__ void gll16(const bf16_t* g, bf16_t* l) {
    __builtin_amdgcn_global_load_lds((const __attribute__((address_space(1))) void*)g,
                                     (__attribute__((address_space(3))) void*)l, 16, 0, 0);
}

// stage a (NI*32)x64 bf16 tile (row-major src, row stride ld elems) into linear LDS [rows][64].
// 16B chunk c of row r stored at slot (c ^ (r&7)). NI gll16 per wave (8 rows each).
template <int NI>
__device__ __forceinline__ void stageT(const bf16_t* __restrict__ src, int ld,
                                       bf16_t* lds, int wave, int lane) {
#pragma unroll
    for (int i = 0; i < NI; i++) {
        int r0 = (wave * NI + i) * 8;
        int r = r0 + (lane >> 3);
        int c = (lane & 7) ^ (r & 7);
        gll16(src + (size_t)r * ld + c * 8, lds + r0 * 64);
    }
}

// read 16B fragment (8 bf16) at (row, 16B-chunk cc) from swizzled [rows][64] tile
__device__ __forceinline__ bf16x8 rdfrag(const bf16_t* lds, int row, int cc) {
    return *(const bf16x8*)(lds + row * 64 + ((cc ^ (row & 7)) * 8));
}

// ---------------- front: weight convert + zero-init + lsr ----------------
__global__ __launch_bounds__(256) void k_front(const float* __restrict__ c1w, const float* __restrict__ c2w,
                                               bf16_t* __restrict__ c1b, bf16_t* __restrict__ c2b,
                                               int* __restrict__ counts, float* __restrict__ degsum,
                                               const float* __restrict__ tin, const float* __restrict__ fcw,
                                               const float* __restrict__ fcb, float4* __restrict__ lsr) {
    int b = blockIdx.x;
    if (b < 192) {
        int i = b * 256 + threadIdx.x;
        const int n0 = 32768, n1 = n0 + 8192, n2 = n1 + 4096, n3 = n2 + 4096;
        if (i < n0) {
            float4 v = ((const float4*)c1w)[i];
            bf16x4 o = {(bf16_t)v.x, (bf16_t)v.y, (bf16_t)v.z, (bf16_t)v.w};
            ((bf16x4*)c1b)[i] = o;
        } else if (i < n1) {
            int j = i - n0;
            float4 v = ((const float4*)c2w)[j];
            bf16x4 o = {(bf16_t)v.x, (bf16_t)v.y, (bf16_t)v.z, (bf16_t)v.w};
            ((bf16x4*)c2b)[j] = o;
        } else if (i < n2) {
            ((int4*)counts)[i - n1] = make_int4(0, 0, 0, 0);
        } else if (i < n3) {
            ((float4*)degsum)[i - n2] = make_float4(0.f, 0.f, 0.f, 0.f);
        }
    } else {
        int row = (b - 192) * 4 + (threadIdx.x >> 6);
        int lane = threadIdx.x & 63;
        const float* tr = tin + (size_t)row * kTC;
        float s0 = 0, s1 = 0, r0 = 0, r1 = 0;
        for (int k = lane; k < kTC; k += 64) {
            float u = fmaxf(tr[k], 0.f);
            s0 += u * fcw[k];
            s1 += u * fcw[512 + k];
            r0 += u * fcw[256 + k];
            r1 += u * fcw[768 + k];
        }
#pragma unroll
        for (int off = 32; off > 0; off >>= 1) {
            s0 += __shfl_down(s0, off); s1 += __shfl_down(s1, off);
            r0 += __shfl_down(r0, off); r1 += __shfl_down(r1, off);
        }
        if (lane == 0) lsr[row] = make_float4(s0 + fcb[0], s1 + fcb[1], r0, r1);
    }
}

// merged: blocks [0,2048) = adj tiles; blocks [2048,4096) = hist chunks (independent work).
// Ah_T[s][j][i] = (argmax==0) + (i==j); accumulates degsum[j] via atomics.
__global__ __launch_bounds__(256) void k_adjhist(const float* __restrict__ gum, const float4* __restrict__ lsr,
                                                 bf16_t* __restrict__ AT, float* __restrict__ degsum,
                                                 const int* __restrict__ col, int* __restrict__ counts) {
    int blk = blockIdx.x;
    if (blk >= 2048) {
        int e = (blk - 2048) * 256 + threadIdx.x;
        if (e < kE) atomicAdd(&counts[col[e]], 1);
        return;
    }
    int s = blk >> 6;
    int a0 = ((blk >> 3) & 7) * 64, b0 = (blk & 7) * 64;
    __shared__ bf16_t tile[64][72];
    int t = threadIdx.x;
    int lb = t & 63, ra = t >> 6;
    int b = b0 + lb;
    float4 pb = lsr[s * kN + b];
#pragma unroll 4
    for (int p = 0; p < 16; p++) {
        int a = a0 + p * 4 + ra;
        float4 qa = lsr[s * kN + a];
        float2 gv = *(const float2*)(gum + ((((size_t)s * kN + a) * kN + b) << 1));
        float u0 = fmaxf(gv.x, 1e-9f);
        float u1 = fmaxf(gv.y, 1e-9f);
        float g0 = -__logf(-__logf(u0));
        float g1 = -__logf(-__logf(u1));
        float v = ((qa.z + pb.x + g0) >= (qa.w + pb.y + g1)) ? 1.f : 0.f;
        if (a == b) v += 1.f;
        tile[lb][p * 4 + ra] = (bf16_t)v;
    }
    __syncthreads();
    int rj = t >> 3, li = (t & 7) * 8;
#pragma unroll
    for (int p = 0; p < 2; p++) {
        int j = p * 32 + rj;
        bf16x8 v = *(const bf16x8*)&tile[j][li];
        *(bf16x8*)(AT + ((size_t)s * kN + b0 + j) * kN + a0 + li) = v;
        float ps = 0;
#pragma unroll
        for (int q = 0; q < 8; q++) ps += (float)v[q];
        ps += __shfl_down(ps, 4);
        ps += __shfl_down(ps, 2);
        ps += __shfl_down(ps, 1);
        if ((t & 7) == 0) atomicAdd(degsum + s * kN + b0 + j, ps);
    }
}

// ---------------- bf16 NT GEMM: C(MxN) = A(MxK) * B(NxK)^T, 128x128 tile, BK=64 ----------------
// GDEC=2: flat 128 blocks, XCD-paired so the 4 x-blocks sharing the B panel land on one XCD L2.
// MODE 2: C = rsqrt(deg[row])*acc + bias[col], no relu.
template <int MODE, int GDEC>
__global__ __launch_bounds__(256) void k_gemm(const bf16_t* __restrict__ A, const bf16_t* __restrict__ B,
                                              bf16_t* __restrict__ C, int K, int lda, int ldb, int ldc,
                                              size_t sA, size_t sB, size_t sC,
                                              const float* __restrict__ degsum, const float* __restrict__ bias) {
    int m0, n0, s;
    {
        int f = blockIdx.x;
        s = ((f >> 5) << 3) | (f & 7);      // [0,32)
        m0 = ((f >> 3) & 3) * 128;
        n0 = 0;
    }
    const bf16_t* Ab = A + sA * s + (size_t)m0 * lda;
    const bf16_t* Bb = B + sB * s + (size_t)n0 * ldb;
    C += sC * s;
    __shared__ __align__(16) bf16_t As[2][128 * 64], Bs[2][128 * 64];
    f32x4 acc[4][4] = {};
    int tid = threadIdx.x;
    int wave = tid >> 6, lane = tid & 63;
    int wm = (wave & 1) * 64, wn = (wave >> 1) * 64;
    int fm = lane & 15, fq = lane >> 4;
    stageT<4>(Ab, lda, As[0], wave, lane);
    stageT<4>(Bb, ldb, Bs[0], wave, lane);
    int cur = 0;
    for (int kb = 0;;) {
        int kn = kb + 64;
        __syncthreads();  // drains vmcnt: buf[cur] staged; buf[cur^1] reads (prev iter) done
        if (kn < K) {
            stageT<4>(Ab + kn, lda, As[cur ^ 1], wave, lane);
            stageT<4>(Bb + kn, ldb, Bs[cur ^ 1], wave, lane);
        }
#pragma unroll
        for (int kk = 0; kk < 2; kk++) {
            bf16x8 af[4], bfr[4];
#pragma unroll
            for (int i = 0; i < 4; i++) {
                af[i] = rdfrag(As[cur], wm + i * 16 + fm, kk * 4 + fq);
                bfr[i] = rdfrag(Bs[cur], wn + i * 16 + fm, kk * 4 + fq);
            }
#pragma unroll
            for (int i = 0; i < 4; i++)
#pragma unroll
                for (int j = 0; j < 4; j++)
                    acc[i][j] = __builtin_amdgcn_mfma_f32_16x16x32_bf16(af[i], bfr[j], acc[i][j], 0, 0, 0);
        }
        kb = kn;
        if (kb >= K) break;
        cur ^= 1;
    }
#pragma unroll
    for (int i = 0; i < 4; i++) {
#pragma unroll
        for (int r = 0; r < 4; r++) {
            int row = wm + i * 16 + fq * 4 + r;
            float sc = rsqrtf(degsum[(size_t)s * kN + m0 + row]);
#pragma unroll
            for (int j = 0; j < 4; j++) {
                int col = n0 + wn + j * 16 + fm;
                float v = sc * acc[i][j][r] + bias[col];
                if constexpr (MODE == 1) v = fmaxf(v, 0.f);
                C[(size_t)(m0 + row) * ldc + col] = (bf16_t)v;
            }
        }
    }
}

// ---- fused dense layer-1 + layer-2-matmul ----
// per (sample s, 64-row tile mt): P1: C1 = relu(rsqrt(deg)*(AT@Z1T^T)+c1b) (64x256) -> LDS
//                                 P2: Z2T tile = rsqrt(deg)*(C1 @ c2wb^T) (64x128, transposed write)
// grid 256, XCD-clustered: all 8 tiles of a sample on one XCD (Z1T panel L2 reuse).
__global__ __launch_bounds__(256) void k_gcn1f(const bf16_t* __restrict__ AT, const bf16_t* __restrict__ Z1T,
                                               const bf16_t* __restrict__ C2W, const float* __restrict__ degsum,
                                               const float* __restrict__ c1b, bf16_t* __restrict__ Z2T) {
    int f = blockIdx.x;
    int s = ((f >> 6) << 3) | (f & 7);
    int mt = (f >> 3) & 7;
    const bf16_t* Ab = AT + (size_t)s * (512 * 512) + (size_t)(mt * 64) * 512;
    const bf16_t* Bb = Z1T + (size_t)s * (256 * 512);
    __shared__ __align__(16) bf16_t smem[40960];  // 80 KB
    // P1 layout: As[2] at 0/4096 (64x64 each), Bs[2] at 8192/24576 (256x64 each)
    // P2 layout (reuse): Hs [64][256] at 0..16384; B2s[2] at 16384/24576 (128x64 each)
    // epi2: T[128][72] at 0..9216
    bf16_t* Hs = smem;
    int tid = threadIdx.x, wave = tid >> 6, lane = tid & 63;
    int fm = lane & 15, fq = lane >> 4;
    f32x4 acc[4][4] = {};
    stageT<2>(Ab, 512, smem, wave, lane);
    stageT<8>(Bb, 512, smem + 8192, wave, lane);
    int cur = 0;
    for (int kb = 0;;) {
        int kn = kb + 64;
        bf16_t* Ac = cur ? smem + 4096 : smem;
        bf16_t* An = cur ? smem : smem + 4096;
        bf16_t* Bc = cur ? smem + 24576 : smem + 8192;
        bf16_t* Bn = cur ? smem + 8192 : smem + 24576;
        __syncthreads();
        if (kn < 512) {
            stageT<2>(Ab + kn, 512, An, wave, lane);
            stageT<8>(Bb + kn, 512, Bn, wave, lane);
        }
        int wn = wave * 64;
#pragma unroll
        for (int kk = 0; kk < 2; kk++) {
            bf16x8 af[4], bfr[4];
#pragma unroll
            for (int i = 0; i < 4; i++) {
                af[i] = rdfrag(Ac, i * 16 + fm, kk * 4 + fq);
                bfr[i] = rdfrag(Bc, wn + i * 16 + fm, kk * 4 + fq);
            }
#pragma unroll
            for (int i = 0; i < 4; i++)
#pragma unroll
                for (int j = 0; j < 4; j++)
                    acc[i][j] = __builtin_amdgcn_mfma_f32_16x16x32_bf16(af[i], bfr[j], acc[i][j], 0, 0, 0);
        }
        kb = kn;
        if (kb >= 512) break;
        cur ^= 1;
    }
    __syncthreads();  // all P1 LDS reads done before Hs overwrite
    stageT<4>(C2W, 256, smem + 16384, wave, lane);  // prefetch B2 tile 0 (region dead post-P1)
    {
        int wn = wave * 64;
#pragma unroll
        for (int i = 0; i < 4; i++) {
#pragma unroll
            for (int r = 0; r < 4; r++) {
                int row = i * 16 + fq * 4 + r;
                float sc = rsqrtf(degsum[(size_t)s * 512 + mt * 64 + row]);
#pragma unroll
                for (int j = 0; j < 4; j++) {
                    int col = wn + j * 16 + fm;
                    float v = fmaxf(sc * acc[i][j][r] + c1b[col], 0.f);
                    int c = col >> 3;
                    int cS = (c & 24) | ((c & 7) ^ (row & 7));
                    Hs[row * 256 + cS * 8 + (col & 7)] = (bf16_t)v;
                }
            }
        }
    }
    f32x4 acc2[4][2] = {};
    int cur2 = 0;
    for (int kb2 = 0;;) {
        int kn2 = kb2 + 64;
        bf16_t* B2c = cur2 ? smem + 24576 : smem + 16384;
        bf16_t* B2n = cur2 ? smem + 16384 : smem + 24576;
        __syncthreads();  // Hs writes visible (iter 0); B2c staged
        if (kn2 < 256) stageT<4>(C2W + kn2, 256, B2n, wave, lane);
        int wc = wave * 32;
#pragma unroll
        for (int kk = 0; kk < 2; kk++) {
            int cbase = (kb2 >> 3) + kk * 4 + fq;  // 16B-chunk col index in [0,32)
            bf16x8 af2[4], bfr2[2];
#pragma unroll
            for (int i = 0; i < 4; i++) {
                int row = i * 16 + fm;
                int cS = (cbase & 24) | ((cbase & 7) ^ (row & 7));
                af2[i] = *(const bf16x8*)&Hs[row * 256 + cS * 8];
            }
#pragma unroll
            for (int j = 0; j < 2; j++) bfr2[j] = rdfrag(B2c, wc + j * 16 + fm, kk * 4 + fq);
#pragma unroll
            for (int i = 0; i < 4; i++)
#pragma unroll
                for (int j = 0; j < 2; j++)
                    acc2[i][j] = __builtin_amdgcn_mfma_f32_16x16x32_bf16(af2[i], bfr2[j], acc2[i][j], 0, 0, 0);
        }
        kb2 = kn2;
        if (kb2 >= 256) break;
        cur2 ^= 1;
    }
    __syncthreads();  // Hs reads done; reuse smem[0..9216) as T[128][72]
    {
        int wc = wave * 32;
#pragma unroll
        for (int i = 0; i < 4; i++) {
#pragma unroll
            for (int r = 0; r < 4; r++) {
                int row = i * 16 + fq * 4 + r;
                float sc = rsqrtf(degsum[(size_t)s * 512 + mt * 64 + row]);
#pragma unroll
                for (int j = 0; j < 2; j++) {
                    int fcol = wc + j * 16 + fm;
                    smem[fcol * 72 + row] = (bf16_t)(sc * acc2[i][j][r]);
                }
            }
        }
    }
    __syncthreads();
    {
        int fr = tid >> 1, half = tid & 1;
        bf16_t* zp = Z2T + ((size_t)(s * 128 + fr)) * 512 + mt * 64 + half * 32;
        const bf16_t* tp = &smem[fr * 72 + half * 32];
#pragma unroll
        for (int q = 0; q < 4; q++) *(bf16x8*)(zp + q * 8) = *(const bf16x8*)(tp + q * 8);
    }
}

// ---- fused GEMM variants producing XW (plain) + ZT (scaled transpose) ----
// AF32: A operand is fp32, reg-staged (issue-early / write-late). F = output cols.
// PAIRXY: flat 256-block grid, XCD-paired so the 2 y-blocks sharing an A-tile co-reside.
// ZT[s][f][i] = rsqrt(deg[row]) * XW[row][f], row = s*512+i. DENSE_ROWS limits ZT writes.
template <bool AF32, int F, int DENSE_ROWS, bool PAIRXY>
__global__ __launch_bounds__(256) void k_gemmT(const void* __restrict__ Ap, const bf16_t* __restrict__ B,
                                               bf16_t* __restrict__ XW, bf16_t* __restrict__ ZT, int K,
                                               const float* __restrict__ degsum) {
    int m0, n0;
    if constexpr (PAIRXY) {
        int f = blockIdx.x;
        m0 = (((f >> 4) << 3) | (f & 7)) * 128;  // [0,128) pair index
        n0 = ((f >> 3) & 1) * 128;
    } else {
        m0 = blockIdx.x * 128;
        n0 = blockIdx.y * 128;
    }
    constexpr int AST = AF32 ? 9216 : 8192;  // per-buffer A elems (padded [128][72] when fp32-staged)
    __shared__ __align__(16) bf16_t smem[2 * AST + 2 * 8192];
    bf16_t* A0 = smem;
    bf16_t* A1 = smem + AST;
    bf16_t* B0 = smem + 2 * AST;
    bf16_t* B1 = smem + 2 * AST + 8192;
    f32x4 acc[4][4] = {};
    int tid = threadIdx.x;
    int wave = tid >> 6, lane = tid & 63;
    int wm = (wave & 1) * 64, wn = (wave >> 1) * 64;
    int fm = lane & 15, fq = lane >> 4;
    int srow = tid >> 3, scol = (tid & 7) * 8;
    const float* Af = (const float*)Ap;
    const bf16_t* Abf = (const bf16_t*)Ap;
    // prologue: stage tile 0
    if constexpr (AF32) {
#pragma unroll
        for (int p = 0; p < 4; p++) {
            int row = p * 32 + srow;
            const float* ap = Af + (size_t)(m0 + row) * K + scol;
            float4 lo = *(const float4*)ap, hi = *(const float4*)(ap + 4);
            bf16x8 o = {(bf16_t)lo.x, (bf16_t)lo.y, (bf16_t)lo.z, (bf16_t)lo.w,
                        (bf16_t)hi.x, (bf16_t)hi.y, (bf16_t)hi.z, (bf16_t)hi.w};
            *(bf16x8*)&A0[row * 72 + scol] = o;
        }
    } else {
        stageT<4>(Abf + (size_t)m0 * K, K, A0, wave, lane);
    }
    stageT<4>(B + (size_t)n0 * K, K, B0, wave, lane);
    int cur = 0;
    for (int kb = 0;;) {
        int kn = kb + 64;
        bool more = kn < K;
        bf16_t* Ac = cur ? A1 : A0;
        bf16_t* An = cur ? A0 : A1;
        bf16_t* Bc = cur ? B1 : B0;
        bf16_t* Bn = cur ? B0 : B1;
        float4 plo[4], phi[4];
        __syncthreads();
        if (more) {
            if constexpr (AF32) {
#pragma unroll
                for (int p = 0; p < 4; p++) {  // issue-early: loads fly during MFMA below
                    int row = p * 32 + srow;
                    const float* ap = Af + (size_t)(m0 + row) * K + kn + scol;
                    plo[p] = *(const float4*)ap;
                    phi[p] = *(const float4*)(ap + 4);
                }
            } else {
                stageT<4>(Abf + (size_t)m0 * K + kn, K, An, wave, lane);
            }
            stageT<4>(B + (size_t)n0 * K + kn, K, Bn, wave, lane);
        }
#pragma unroll
        for (int kk = 0; kk < 2; kk++) {
            bf16x8 af[4], bfr[4];
#pragma unroll
            for (int i = 0; i < 4; i++) {
                if constexpr (AF32)
                    af[i] = *(const bf16x8*)&Ac[(wm + i * 16 + fm) * 72 + kk * 32 + fq * 8];
                else
                    af[i] = rdfrag(Ac, wm + i * 16 + fm, kk * 4 + fq);
                bfr[i] = rdfrag(Bc, wn + i * 16 + fm, kk * 4 + fq);
            }
#pragma unroll
            for (int i = 0; i < 4; i++)
#pragma unroll
                for (int j = 0; j < 4; j++)
                    acc[i][j] = __builtin_amdgcn_mfma_f32_16x16x32_bf16(af[i], bfr[j], acc[i][j], 0, 0, 0);
        }
        if constexpr (AF32) {
            if (more) {  // write-late: cvt + ds_write after compute
#pragma unroll
                for (int p = 0; p < 4; p++) {
                    int row = p * 32 + srow;
                    bf16x8 o = {(bf16_t)plo[p].x, (bf16_t)plo[p].y, (bf16_t)plo[p].z, (bf16_t)plo[p].w,
                                (bf16_t)phi[p].x, (bf16_t)phi[p].y, (bf16_t)phi[p].z, (bf16_t)phi[p].w};
                    *(bf16x8*)&An[row * 72 + scol] = o;
                }
            }
        }
        kb = kn;
        if (kb >= K) break;
        cur ^= 1;
    }
    // write XW (unscaled) + stage scaled values into LDS transposed
    bool doT = (m0 < DENSE_ROWS);
    __syncthreads();  // all LDS ops of the K-loop complete before reuse as T[128][136]
#pragma unroll
    for (int i = 0; i < 4; i++) {
#pragma unroll
        for (int r = 0; r < 4; r++) {
            int row = wm + i * 16 + fq * 4 + r;
            float sc = doT ? rsqrtf(degsum[m0 + row]) : 0.f;
#pragma unroll
            for (int j = 0; j < 4; j++) {
                int col = wn + j * 16 + fm;
                float v = acc[i][j][r];
                XW[(size_t)(m0 + row) * F + n0 + col] = (bf16_t)v;
                if (doT) smem[col * 136 + row] = (bf16_t)(sc * v);
            }
        }
    }
    if (doT) {
        __syncthreads();
        int fr = tid >> 1, hi = (tid & 1) * 64;
        bf16_t* zrow = ZT + ((size_t)(m0 >> 9) * F + n0 + fr) * kN + (m0 & 511) + hi;
#pragma unroll
        for (int q = 0; q < 8; q++)
            *(bf16x8*)(zrow + q * 8) = *(const bf16x8*)&smem[fr * 136 + hi + q * 8];
    }
}

// ---------------- sparse path ----------------

// single block, 1024 threads; padded LDS indexing (j + j/32) to avoid bank conflicts
__global__ __launch_bounds__(1024) void k_scan(const int* __restrict__ counts, int* __restrict__ offsets,
                                               int* __restrict__ cursor, float* __restrict__ dis_s) {
    __shared__ int ldc_[16896];
    __shared__ int sums[1024];
    int t = threadIdx.x;
#define IDX(j) ((j) + ((j) >> 5))
    for (int i = 0; i < 16; i++) {
        int g = i * 1024 + t;
        int c = counts[g];
        ldc_[IDX(g)] = c;
        dis_s[g] = rsqrtf((float)(c + 1));  // deg includes self loop
    }
    __syncthreads();
    int s = 0;
    for (int i = 0; i < 16; i++) s += ldc_[IDX(t * 16 + i)];
    sums[t] = s;
    __syncthreads();
    for (int off = 1; off < 1024; off <<= 1) {
        int y = (t >= off) ? sums[t - off] : 0;
        __syncthreads();
        sums[t] += y;
        __syncthreads();
    }
    int run = sums[t] - s;  // exclusive prefix
    for (int i = 0; i < 16; i++) {
        int j = t * 16 + i;
        int c = ldc_[IDX(j)];
        ldc_[IDX(j)] = run;
        run += c;
    }
    __syncthreads();
    for (int i = 0; i < 16; i++) {
        int g = i * 1024 + t;
        int o = ldc_[IDX(g)];
        offsets[g] = o;
        cursor[g] = o;
    }
#undef IDX
}

__global__ __launch_bounds__(256) void k_fill(const int* __restrict__ row, const int* __restrict__ col,
                                              int* __restrict__ cursor, int* __restrict__ list) {
    int e = blockIdx.x * 256 + threadIdx.x;
    if (e < kE) {
        int p = atomicAdd(&cursor[col[e]], 1);
        list[p] = row[e];
    }
}

// out[j,f8..f8+7] via bf16x8 gathers; OUT row j, ld 256. List-prefetch software pipeline.
template <int F, bool RELU>
__global__ __launch_bounds__(256) void k_sagg(const bf16_t* __restrict__ XW, int rowOffIn,
                                              const int* __restrict__ list, const int* __restrict__ offsets,
                                              const int* __restrict__ counts, const float* __restrict__ dis_s,
                                              const float* __restrict__ bias, bf16_t* __restrict__ OUT,
                                              int outColOff) {
    constexpr int TPR = F / 8;        // threads per row
    constexpr int RPB = 256 / TPR;    // rows per block
    int j = blockIdx.x * RPB + threadIdx.x / TPR;
    int f8 = (threadIdx.x % TPR) * 8;
    float dj = dis_s[j];
    const bf16_t* base = XW + (size_t)rowOffIn * F;
    float acc[8];
    {
        bf16x8 v = *(const bf16x8*)(base + (size_t)j * F + f8);
#pragma unroll
        for (int q = 0; q < 8; q++) acc[q] = dj * (float)v[q];
    }
    int off = offsets[j], cnt = counts[j];
    int e = 0;
    int nb = cnt & ~7;
    if (nb) {
        int r[8];
#pragma unroll
        for (int q = 0; q < 8; q++) r[q] = list[off + q];
        while (true) {
            int en = e + 8;
            bool more = en < nb;
            int rn[8];
            if (more) {
#pragma unroll
                for (int q = 0; q < 8; q++) rn[q] = list[off + en + q];
            }
            float d[8];
#pragma unroll
            for (int q = 0; q < 8; q++) d[q] = dis_s[r[q]];
            bf16x8 v0 = *(const bf16x8*)(base + (size_t)r[0] * F + f8);
            bf16x8 v1 = *(const bf16x8*)(base + (size_t)r[1] * F + f8);
            bf16x8 v2 = *(const bf16x8*)(base + (size_t)r[2] * F + f8);
            bf16x8 v3 = *(const bf16x8*)(base + (size_t)r[3] * F + f8);
            bf16x8 v4 = *(const bf16x8*)(base + (size_t)r[4] * F + f8);
            bf16x8 v5 = *(const bf16x8*)(base + (size_t)r[5] * F + f8);
            bf16x8 v6 = *(const bf16x8*)(base + (size_t)r[6] * F + f8);
            bf16x8 v7 = *(const bf16x8*)(base + (size_t)r[7] * F + f8);
#pragma unroll
            for (int q = 0; q < 8; q++)
                acc[q] += ((d[0] * (float)v0[q] + d[1] * (float)v1[q]) + (d[2] * (float)v2[q] + d[3] * (float)v3[q])) +
                          ((d[4] * (float)v4[q] + d[5] * (float)v5[q]) + (d[6] * (float)v6[q] + d[7] * (float)v7[q]));
            e = en;
            if (!more) break;
#pragma unroll
            for (int q = 0; q < 8; q++) r[q] = rn[q];
        }
    }
    for (; e + 4 <= cnt; e += 4) {
        int r0 = list[off + e], r1 = list[off + e + 1], r2 = list[off + e + 2], r3 = list[off + e + 3];
        float d0 = dis_s[r0], d1 = dis_s[r1], d2 = dis_s[r2], d3 = dis_s[r3];
        bf16x8 v0 = *(const bf16x8*)(base + (size_t)r0 * F + f8);
        bf16x8 v1 = *(const bf16x8*)(base + (size_t)r1 * F + f8);
        bf16x8 v2 = *(const bf16x8*)(base + (size_t)r2 * F + f8);
        bf16x8 v3 = *(const bf16x8*)(base + (size_t)r3 * F + f8);
#pragma unroll
        for (int q = 0; q < 8; q++)
            acc[q] += (d0 * (float)v0[q] + d1 * (float)v1[q]) + (d2 * (float)v2[q] + d3 * (float)v3[q]);
    }
    for (; e < cnt; e++) {
        int r = list[off + e];
        float d = dis_s[r];
        bf16x8 v = *(const bf16x8*)(base + (size_t)r * F + f8);
#pragma unroll
        for (int q = 0; q < 8; q++) acc[q] += d * (float)v[q];
    }
    bf16x8 o;
#pragma unroll
    for (int q = 0; q < 8; q++) {
        float v = dj * acc[q] + bias[f8 + q];
        if (RELU) v = fmaxf(v, 0.f);
        o[q] = (bf16_t)v;
    }
    *(bf16x8*)(OUT + (size_t)j * 256 + outColOff + f8) = o;
}

// ---------------- FCN head ----------------
// register-direct split-K MFMA: 256 blocks, block b covers K chunk [b*512, b*512+512).
__global__ __launch_bounds__(256) void k_fcn1(const bf16_t* __restrict__ EMB, const float* __restrict__ W1,
                                              float* __restrict__ partials) {
    int tid = threadIdx.x, wave = tid >> 6, lane = tid & 63;
    int fm = lane & 15, fq = lane >> 4;
    int kb0 = blockIdx.x * 512;
    f32x4 acc[2][4] = {};
#pragma unroll 4
    for (int ks = 0; ks < 512; ks += 32) {
        int k = kb0 + ks + fq * 8;
        bf16x8 a0 = *(const bf16x8*)(EMB + (size_t)fm * 131072 + k);
        bf16x8 a1 = *(const bf16x8*)(EMB + (size_t)(16 + fm) * 131072 + k);
        bf16x8 bfr[4];
#pragma unroll
        for (int j = 0; j < 4; j++) {
            int n = wave * 64 + j * 16 + fm;
            const float* p = W1 + (size_t)n * 131072 + k;
            float4 lo = *(const float4*)p;
            float4 hi = *(const float4*)(p + 4);
            bf16x8 b = {(bf16_t)lo.x, (bf16_t)lo.y, (bf16_t)lo.z, (bf16_t)lo.w,
                        (bf16_t)hi.x, (bf16_t)hi.y, (bf16_t)hi.z, (bf16_t)hi.w};
            bfr[j] = b;
        }
#pragma unroll
        for (int j = 0; j < 4; j++) {
            acc[0][j] = __builtin_amdgcn_mfma_f32_16x16x32_bf16(a0, bfr[j], acc[0][j], 0, 0, 0);
            acc[1][j] = __builtin_amdgcn_mfma_f32_16x16x32_bf16(a1, bfr[j], acc[1][j], 0, 0, 0);
        }
    }
    float* P = partials + (size_t)blockIdx.x * 8192;
#pragma unroll
    for (int i = 0; i < 2; i++)
#pragma unroll
        for (int j = 0; j < 4; j++)
#pragma unroll
            for (int r = 0; r < 4; r++)
                P[(size_t)(i * 16 + fq * 4 + r) * 256 + wave * 64 + j * 16 + fm] = acc[i][j][r];
}

// reduce 256 partials -> h1pre[8192]. 256 blocks: block b covers 32 outputs, 8-way slice split.
__global__ __launch_bounds__(256) void k_reduce(const float* __restrict__ partials, float* __restrict__ h1pre) {
    __shared__ float red[8][32];
    int t = threadIdx.x;
    int el = t & 31, q = t >> 5;
    int e = blockIdx.x * 32 + el;
    float s = 0;
#pragma unroll 8
    for (int i = 0; i < 32; i++) s += partials[(size_t)(q * 32 + i) * 8192 + e];
    red[q][el] = s;
    __syncthreads();
    if (t < 32) {
        float r = 0;
#pragma unroll
        for (int qq = 0; qq < 8; qq++) r += red[qq][t];
        h1pre[blockIdx.x * 32 + t] = r;
    }
}

// final: h1 = leaky(h1pre + b1); h2 = leaky(h1@W2^T+b2); out = h2@W3^T+b3
__global__ __launch_bounds__(256) void k_head(const float* __restrict__ h1pre, const float* __restrict__ b1,
                                              const float* __restrict__ W2, const float* __restrict__ b2,
                                              const float* __restrict__ W3, const float* __restrict__ b3,
                                              float* __restrict__ out) {
    __shared__ float h1s[32][256];
    __shared__ float h2s[32][32];
    int t = threadIdx.x;
    for (int i = 0; i < 32; i++) {
        float s = h1pre[i * 256 + t] + b1[t];
        h1s[i][t] = (s > 0.f) ? s : 0.2f * s;
    }
    __syncthreads();
    for (int p = 0; p < 4; p++) {
        int id = p * 256 + t, si = id >> 5, o2 = id & 31;
        float s = 0;
        for (int k = 0; k < 256; k++) s += h1s[si][k] * W2[o2 * 256 + k];
        s += b2[o2];
        h2s[si][o2] = (s > 0.f) ? s : 0.2f * s;
    }
    __syncthreads();
    if (t < 64) {
        int si = t >> 1, o3 = t & 1;
        float s = 0;
#pragma unroll
        for (int k = 0; k < 32; k++) s += h2s[si][k] * W3[o3 * 32 + k];
        out[si * 2 + o3] = s + b3[o3];
    }
}

// ---------------- launcher ----------------

extern "C" void kernel_launch(void* const* d_in, const int* in_sizes, int n_in,
                              void* d_out, int out_size, void* d_ws, size_t ws_size,
                              hipStream_t stream) {
    const float* x = (const float*)d_in[0];
    const float* t = (const float*)d_in[1];
    const float* gum = (const float*)d_in[2];
    const int* eidx = (const int*)d_in[3];
    const float* c1w = (const float*)d_in[4];
    const float* c1b = (const float*)d_in[5];
    const float* c2w = (const float*)d_in[6];
    const float* c2b = (const float*)d_in[7];
    const float* fcw = (const float*)d_in[8];
    const float* fcb = (const float*)d_in[9];
    const float* w1 = (const float*)d_in[10];
    const float* b1 = (const float*)d_in[11];
    const float* w2 = (const float*)d_in[12];
    const float* b2 = (const float*)d_in[13];
    const float* w3 = (const float*)d_in[14];
    const float* b3 = (const float*)d_in[15];
    float* out = (float*)d_out;
    (void)in_sizes; (void)n_in; (void)out_size; (void)ws_size;

    char* ws = (char*)d_ws;
    size_t off = 0;
    auto alloc = [&](size_t bytes) -> char* {
        char* p = ws + off;
        off += (bytes + 255) & ~size_t(255);
        return p;
    };
    bf16_t* c1wb = (bf16_t*)alloc((size_t)256 * 512 * 2);
    bf16_t* c2wb = (bf16_t*)alloc((size_t)128 * 256 * 2);
    float4* lsr = (float4*)alloc((size_t)kNTOT * 16);
    bf16_t* AT = (bf16_t*)alloc((size_t)kBZ * kN * kN * 2);          // 16.8 MB
    float* degsum = (float*)alloc((size_t)kNTOT * 4);
    bf16_t* XW1_EMB = (bf16_t*)alloc((size_t)kNTOT * 256 * 2);       // 8.4 MB (XW1 then EMB)
    bf16_t* Z1T = (bf16_t*)alloc((size_t)kBZ * 256 * 512 * 2);       // 8.4 MB
    bf16_t* H = (bf16_t*)alloc((size_t)32768 * 256 * 2);             // sparse rows 16384.. used
    bf16_t* XW2 = (bf16_t*)alloc((size_t)32768 * 128 * 2);           // sparse rows 16384.. used
    bf16_t* Z2T = (bf16_t*)alloc((size_t)kBZ * 128 * 512 * 2);       // 4.2 MB
    int* counts = (int*)alloc((size_t)kNTOT * 4);
    int* offsets = (int*)alloc((size_t)kNTOT * 4);
    int* cursor = (int*)alloc((size_t)kNTOT * 4);
    float* diss = (float*)alloc((size_t)kNTOT * 4);
    int* list = (int*)alloc((size_t)kE * 4);
    float* partials = (float*)alloc((size_t)256 * 8192 * 4);         // 8.4 MB
    float* h1pre = (float*)alloc((size_t)8192 * 4);

    bf16_t* XW1 = XW1_EMB;
    bf16_t* EMB = XW1_EMB;  // EMB written only after XW1's last read (sparse L1)

    // front: weight cvt + zero counts/degsum + lsr
    k_front<<<4288, 256, 0, stream>>>(c1w, c2w, c1wb, c2wb, counts, degsum, t, fcw, fcb, lsr);
    // adj tiles + edge histogram (independent work, one dispatch)
    k_adjhist<<<4096, 256, 0, stream>>>(gum, lsr, AT, degsum, eidx + kE, counts);
    k_scan<<<1, 1024, 0, stream>>>(counts, offsets, cursor, diss);
    k_fill<<<2048, 256, 0, stream>>>(eidx, eidx + kE, cursor, list);
    // XW1 = x @ conv1_w^T (fp32 A reg-staged) + Z1T scaled transpose; XCD-paired grid
    k_gemmT<true, 256, kNTOT, true><<<256, 256, 0, stream>>>(x, c1wb, XW1, Z1T, 512, degsum);
    // fused dense L1 + L2-matmul -> Z2T (H-dense never materialized)
    k_gcn1f<<<256, 256, 0, stream>>>(AT, Z1T, c2wb, degsum, c1b, Z2T);
    // sparse layer 1 -> H rows 16384..
    k_sagg<256, true><<<2048, 256, 0, stream>>>(XW1, 0, list, offsets, counts, diss, c1b,
                                                H + (size_t)16384 * 256, 0);
    // sparse-only layer-2 matmul: XW2[16384..] = H[16384..] @ conv2_w^T
    k_gemmT<false, 128, 0, false><<<dim3(128, 1, 1), 256, 0, stream>>>(H + (size_t)16384 * 256, c2wb,
                                                                       XW2 + (size_t)16384 * 128, Z2T, 256, degsum);
    // dense layer 2 -> EMB cols 0..127; XCD-clustered grid
    k_gemm<2, 2><<<128, 256, 0, stream>>>(AT, Z2T, EMB, 512, 512, 512, 256,
                                          (size_t)512 * 512, (size_t)128 * 512, (size_t)512 * 256,
                                          degsum, c2b);
    // sparse layer 2 -> EMB cols 128..255
    k_sagg<128, false><<<1024, 256, 0, stream>>>(XW2, 16384, list, offsets, counts, diss, c2b, EMB, 128);
    // FCN head
    k_fcn1<<<256, 256, 0, stream>>>(EMB, w1, partials);
    k_reduce<<<256, 256, 0, stream>>>(partials, h1pre);
    k_head<<<1, 256, 0, stream>>>(h1pre, b1, w2, b2, w3, b3, out);
}